// Round 7
// baseline (465.027 us; speedup 1.0000x reference)
//
#include <hip/hip_runtime.h>
#include <hip/hip_bf16.h>
#include <cstddef>

// Problem constants
#define BATCH 16384
#define IND   784
#define HID   768
#define NEXP  8
#define KT13  13          // ceil(784/64) K-tiles, padded to 832

typedef short bf16x8 __attribute__((ext_vector_type(8)));
typedef float f32x4  __attribute__((ext_vector_type(4)));
typedef unsigned short ushort_t;

#define GLD16(g, l)                                                            \
  __builtin_amdgcn_global_load_lds(                                            \
      (const __attribute__((address_space(1))) unsigned int*)(g),              \
      (__attribute__((address_space(3))) unsigned int*)(l), 16, 0, 0)

// ---------------------------------------------------------------- K0: W_exp [e][h][d] f32 -> Wt [e][d][h] bf16
__global__ __launch_bounds__(256) void k_wtrans(const float* __restrict__ Wexp,
                                                __hip_bfloat16* __restrict__ Wt)
{
  __shared__ float tile[32][33];
  const int e = blockIdx.z;
  const int h0 = blockIdx.x * 32, d0 = blockIdx.y * 32;
  const int tx = threadIdx.x & 31, ty = threadIdx.x >> 5;   // 32 x 8
  const float* src = Wexp + ((size_t)e * HID + h0) * HID + d0;
  #pragma unroll
  for (int i = 0; i < 4; i++)
    tile[ty + 8 * i][tx] = src[(size_t)(ty + 8 * i) * HID + tx];
  __syncthreads();
  __hip_bfloat16* dst = Wt + ((size_t)e * HID + d0) * HID + h0;
  #pragma unroll
  for (int i = 0; i < 4; i++)
    dst[(size_t)(ty + 8 * i) * HID + tx] = __float2bfloat16(tile[tx][ty + 8 * i]);
}

// ---------------------------------------------------------------- helpers: bf16 split
__device__ inline ushort_t bf16_rne(float f) {
  union { float f; unsigned u; } v; v.f = f;
  unsigned r = v.u + 0x7fffu + ((v.u >> 16) & 1u);
  return (ushort_t)(r >> 16);
}
__device__ inline float bf16_to_f(ushort_t h) {
  union { unsigned u; float f; } v; v.u = ((unsigned)h) << 16;
  return v.f;
}

// ---------------------------------------------------------------- K0a: pack x -> bf16 hi/lo tiles [mt][kt][128][64] (unswizzled)
__global__ __launch_bounds__(256) void k_packA(const float* __restrict__ x,
                                               ushort_t* __restrict__ Ahi,
                                               ushort_t* __restrict__ Alo)
{
  const int kt = blockIdx.x, mt = blockIdx.y;
  const size_t tbase = ((size_t)mt * KT13 + kt) * 8192;
  const int kb = kt * 64;
  #pragma unroll
  for (int i = 0; i < 4; i++) {
    int id = i * 256 + threadIdx.x;             // 1024 chunks of 8
    int r = id >> 3, c = id & 7;
    int row = mt * 128 + r;
    int k0 = kb + c * 8;
    float v[8];
    if (k0 + 8 <= IND) {
      const float4* p = reinterpret_cast<const float4*>(x + (size_t)row * IND + k0);
      float4 a = p[0], b = p[1];
      v[0] = a.x; v[1] = a.y; v[2] = a.z; v[3] = a.w;
      v[4] = b.x; v[5] = b.y; v[6] = b.z; v[7] = b.w;
    } else {
      #pragma unroll
      for (int j = 0; j < 8; j++) v[j] = (k0 + j < IND) ? x[(size_t)row * IND + k0 + j] : 0.f;
    }
    ushort_t hi[8], lo[8];
    #pragma unroll
    for (int j = 0; j < 8; j++) {
      hi[j] = bf16_rne(v[j]);
      lo[j] = bf16_rne(v[j] - bf16_to_f(hi[j]));
    }
    size_t dst = tbase + (size_t)r * 64 + c * 8;
    *reinterpret_cast<uint4*>(Ahi + dst) = *reinterpret_cast<uint4*>(hi);
    *reinterpret_cast<uint4*>(Alo + dst) = *reinterpret_cast<uint4*>(lo);
  }
}

// ---------------------------------------------------------------- K0b: pack W_in^T -> bf16 hi/lo tiles [nt][kt][128][64] (unswizzled)
__global__ __launch_bounds__(256) void k_packB(const float* __restrict__ W,
                                               ushort_t* __restrict__ Bhi,
                                               ushort_t* __restrict__ Blo)
{
  const int kt = blockIdx.x, nt = blockIdx.y;
  const size_t tbase = ((size_t)nt * KT13 + kt) * 8192;
  const int kb = kt * 64;
  #pragma unroll
  for (int i = 0; i < 4; i++) {
    int id = i * 256 + threadIdx.x;
    int r = id >> 3, c = id & 7;                 // r = output col index within tile
    int n = nt * 128 + r;
    int k0 = kb + c * 8;
    float v[8];
    #pragma unroll
    for (int j = 0; j < 8; j++)
      v[j] = (k0 + j < IND) ? W[(size_t)(k0 + j) * HID + n] : 0.f;
    ushort_t hi[8], lo[8];
    #pragma unroll
    for (int j = 0; j < 8; j++) {
      hi[j] = bf16_rne(v[j]);
      lo[j] = bf16_rne(v[j] - bf16_to_f(hi[j]));
    }
    size_t dst = tbase + (size_t)r * 64 + c * 8;
    *reinterpret_cast<uint4*>(Bhi + dst) = *reinterpret_cast<uint4*>(hi);
    *reinterpret_cast<uint4*>(Blo + dst) = *reinterpret_cast<uint4*>(lo);
  }
}

// ---------------------------------------------------------------- K1: proj = x @ W_in + b_in  (split-bf16 3-pass MFMA)
// no-LDS: fragments gathered directly from global (L2/L3-resident tiles); XCD-swizzled grid
__global__ __launch_bounds__(256) void k_proj3(const ushort_t* __restrict__ Ahi,
                                               const ushort_t* __restrict__ Alo,
                                               const ushort_t* __restrict__ Bhi,
                                               const ushort_t* __restrict__ Blo,
                                               const float* __restrict__ bias,
                                               float* __restrict__ out,
                                               float* __restrict__ pm)
{
  // bijective XCD swizzle: 768 = 8 XCDs x 96; each XCD gets 16 mt x 6 nt
  const int bid = blockIdx.x;
  const int sid = (bid & 7) * 96 + (bid >> 3);
  const int mt = sid / 6, nt = sid - 6 * mt;
  const int tid = threadIdx.x, lane = tid & 63, w = tid >> 6;
  const int m0 = (w >> 1) * 64, n0 = (w & 1) * 64;
  const int l15 = lane & 15, g = lane >> 4;

  f32x4 acc[4][4];
  #pragma unroll
  for (int i = 0; i < 4; i++)
    #pragma unroll
    for (int j = 0; j < 4; j++) acc[i][j] = (f32x4){0.f, 0.f, 0.f, 0.f};

  const size_t abase = (size_t)mt * KT13 * 8192;
  const size_t bbase = (size_t)nt * KT13 * 8192;

  for (int kt = 0; kt < KT13; kt++) {
    const ushort_t* ath = Ahi + abase + (size_t)kt * 8192;
    const ushort_t* atl = Alo + abase + (size_t)kt * 8192;
    const ushort_t* bth = Bhi + bbase + (size_t)kt * 8192;
    const ushort_t* btl = Blo + bbase + (size_t)kt * 8192;
    #pragma unroll
    for (int ks = 0; ks < 2; ks++) {
      bf16x8 ah[4], al[4], bh[4], blv[4];
      #pragma unroll
      for (int i = 0; i < 4; i++) {
        int oa = (m0 + 16 * i + l15) * 64 + (4 * ks + g) * 8;
        ah[i]  = *reinterpret_cast<const bf16x8*>(ath + oa);
        al[i]  = *reinterpret_cast<const bf16x8*>(atl + oa);
        int ob = (n0 + 16 * i + l15) * 64 + (4 * ks + g) * 8;
        bh[i]  = *reinterpret_cast<const bf16x8*>(bth + ob);
        blv[i] = *reinterpret_cast<const bf16x8*>(btl + ob);
      }
      #pragma unroll
      for (int i = 0; i < 4; i++)
        #pragma unroll
        for (int j = 0; j < 4; j++) {
          acc[i][j] = __builtin_amdgcn_mfma_f32_16x16x32_bf16(ah[i], bh[j],  acc[i][j], 0, 0, 0);
          acc[i][j] = __builtin_amdgcn_mfma_f32_16x16x32_bf16(ah[i], blv[j], acc[i][j], 0, 0, 0);
          acc[i][j] = __builtin_amdgcn_mfma_f32_16x16x32_bf16(al[i], bh[j],  acc[i][j], 0, 0, 0);
        }
    }
  }

  // epilogue: C layout col=lane&15, row=(lane>>4)*4+reg
  float bl[4];
  #pragma unroll
  for (int j = 0; j < 4; j++) bl[j] = bias[nt * 128 + n0 + 16 * j + l15];
  #pragma unroll
  for (int i = 0; i < 4; i++) {
    #pragma unroll
    for (int q = 0; q < 4; q++) {
      int m = mt * 128 + m0 + 16 * i + g * 4 + q;
      #pragma unroll
      for (int j = 0; j < 4; j++) {
        int n = nt * 128 + n0 + 16 * j + l15;
        out[(size_t)m * HID + n] = acc[i][j][q] + bl[j];
      }
    }
  }
  // deterministic row-sum partials for mean: 12 slots/row (6 nt x 2 wave-halves)
  const float blsum = bl[0] + bl[1] + bl[2] + bl[3];
  const size_t pslot = (size_t)(nt * 2 + (w & 1)) * BATCH;
  #pragma unroll
  for (int i = 0; i < 4; i++) {
    #pragma unroll
    for (int q = 0; q < 4; q++) {
      float s = acc[i][0][q] + acc[i][1][q] + acc[i][2][q] + acc[i][3][q] + blsum;
      s += __shfl_xor(s, 1); s += __shfl_xor(s, 2);
      s += __shfl_xor(s, 4); s += __shfl_xor(s, 8);
      if (l15 == 0)
        pm[pslot + mt * 128 + m0 + 16 * i + g * 4 + q] = s;
    }
  }
}

// ---------------------------------------------------------------- K1c: enh = proj + feats @ W_ph + b_ph  (in place; means fused)
__global__ __launch_bounds__(256) void k_phasor(const float* __restrict__ pm,
                                                const float* __restrict__ Wph,
                                                const float* __restrict__ bph,
                                                float* __restrict__ enh)
{
  __shared__ float Fs[64][132];   // [k][m] transposed feats
  __shared__ float Ws[64][128];   // [k][n]
  __shared__ float mlds[128];
  const int t  = threadIdx.x;
  const int bm = blockIdx.y * 128, bn = blockIdx.x * 128;
  if (t < 128) {
    float s = 0.f;
    #pragma unroll
    for (int k = 0; k < 12; k++) s += pm[(size_t)k * BATCH + bm + t];
    mlds[t] = s * (1.0f / 768.0f);
  }
  __syncthreads();
  {
    const int r = t >> 1;
    const float mn = mlds[r];
    if ((t & 1) == 0) {
      #pragma unroll
      for (int j = 0; j < 32; j++) Fs[j][r] = sinf(mn * (7.0f * (j + 1)));
    } else {
      #pragma unroll
      for (int j = 0; j < 32; j++) Fs[32 + j][r] = cosf(mn * (7.0f * (j + 1)));
    }
  }
  #pragma unroll
  for (int i = 0; i < 8; i++) {
    int f4 = i * 256 + t;
    int k = f4 >> 5, n4 = (f4 & 31) * 4;
    *reinterpret_cast<float4*>(&Ws[k][n4]) =
        *reinterpret_cast<const float4*>(Wph + (size_t)k * HID + bn + n4);
  }
  __syncthreads();

  const int m0 = (t >> 4) * 8, n0 = (t & 15) * 8;
  float acc[8][8];
  #pragma unroll
  for (int i = 0; i < 8; i++)
    #pragma unroll
    for (int j = 0; j < 8; j++) acc[i][j] = 0.f;
  #pragma unroll 4
  for (int k = 0; k < 64; k++) {
    float a[8], b[8];
    *reinterpret_cast<float4*>(&a[0]) = *reinterpret_cast<const float4*>(&Fs[k][m0]);
    *reinterpret_cast<float4*>(&a[4]) = *reinterpret_cast<const float4*>(&Fs[k][m0 + 4]);
    *reinterpret_cast<float4*>(&b[0]) = *reinterpret_cast<const float4*>(&Ws[k][n0]);
    *reinterpret_cast<float4*>(&b[4]) = *reinterpret_cast<const float4*>(&Ws[k][n0 + 4]);
    #pragma unroll
    for (int i = 0; i < 8; i++)
      #pragma unroll
      for (int j = 0; j < 8; j++) acc[i][j] = fmaf(a[i], b[j], acc[i][j]);
  }
  float bl[8];
  #pragma unroll
  for (int j = 0; j < 8; j++) bl[j] = bph[bn + n0 + j];
  #pragma unroll
  for (int i = 0; i < 8; i++) {
    float* rowp = enh + (size_t)(bm + m0 + i) * HID + bn + n0;
    float4 p0 = *reinterpret_cast<float4*>(rowp);
    float4 p1 = *reinterpret_cast<float4*>(rowp + 4);
    p0.x += acc[i][0] + bl[0]; p0.y += acc[i][1] + bl[1];
    p0.z += acc[i][2] + bl[2]; p0.w += acc[i][3] + bl[3];
    p1.x += acc[i][4] + bl[4]; p1.y += acc[i][5] + bl[5];
    p1.z += acc[i][6] + bl[6]; p1.w += acc[i][7] + bl[7];
    *reinterpret_cast<float4*>(rowp)     = p0;
    *reinterpret_cast<float4*>(rowp + 4) = p1;
  }
}

// ---------------------------------------------------------------- K2: top-5 gains, attended(bf16), gate partials, colsum partials
__global__ __launch_bounds__(256) void k_attend(const float* __restrict__ enh,
                                                const float* __restrict__ Wg,
                                                __hip_bfloat16* __restrict__ attb,
                                                float* __restrict__ glog,
                                                float* __restrict__ partials)
{
  __shared__ float WgT[8][768];
  __shared__ float cs[4][768];
  const int t = threadIdx.x, lane = t & 63, w = t >> 6;
  for (int i = t; i < 768 * 8; i += 256) { int c = i >> 3, e = i & 7; WgT[e][c] = Wg[i]; }
  for (int i = t; i < 4 * 768; i += 256) cs[i / 768][i % 768] = 0.f;
  __syncthreads();

  for (int rr = 0; rr < 8; ++rr) {
    const int row = blockIdx.x * 32 + rr * 4 + w;
    const float* er = enh + (size_t)row * HID;
    float o[12], s[12];
    #pragma unroll
    for (int j = 0; j < 12; j++) { o[j] = er[lane + 64 * j]; s[j] = o[j]; }

    int wc[5];
    #pragma unroll
    for (int k = 0; k < 5; k++) {
      float v = -3.4e38f; int c = 0x7fffffff;
      #pragma unroll
      for (int j = 0; j < 12; j++)
        if (s[j] > v) { v = s[j]; c = lane + 64 * j; }          // ascending j: low idx on tie
      #pragma unroll
      for (int off = 32; off; off >>= 1) {
        float ov = __shfl_xor(v, off); int oc = __shfl_xor(c, off);
        if (ov > v || (ov == v && oc < c)) { v = ov; c = oc; }  // jax tie rule: lower index
      }
      wc[k] = c;
      if (lane == (c & 63)) {
        #pragma unroll
        for (int j = 0; j < 12; j++) if (j == (c >> 6)) s[j] = -3.4e38f;
      }
    }

    float a[12];
    #pragma unroll
    for (int j = 0; j < 12; j++) a[j] = o[j];
    float wv = 1.0f;
    #pragma unroll
    for (int k = 0; k < 5; k++) {
      int c = wc[k];
      if (lane == (c & 63)) {
        #pragma unroll
        for (int j = 0; j < 12; j++) if (j == (c >> 6)) a[j] = o[j] * (1.0f + wv);
      }
      wv *= 0.7f;
    }
    #pragma unroll
    for (int j = 0; j < 12; j++)
      attb[(size_t)row * HID + lane + 64 * j] = __float2bfloat16(a[j]);
    #pragma unroll
    for (int j = 0; j < 12; j++) cs[w][lane + 64 * j] += a[j];

    float p[8];
    #pragma unroll
    for (int e = 0; e < 8; e++) p[e] = 0.f;
    #pragma unroll
    for (int j = 0; j < 12; j++) {
      int c = lane + 64 * j;
      #pragma unroll
      for (int e = 0; e < 8; e++) p[e] = fmaf(a[j], WgT[e][c], p[e]);
    }
    #pragma unroll
    for (int e = 0; e < 8; e++) {
      #pragma unroll
      for (int off = 32; off; off >>= 1) p[e] += __shfl_xor(p[e], off);
    }
    if (lane == 0) {
      #pragma unroll
      for (int e = 0; e < 8; e++) glog[(size_t)row * 8 + e] = p[e];
    }
  }
  __syncthreads();
  for (int i = t; i < 768; i += 256)
    partials[(size_t)blockIdx.x * 768 + i] = cs[0][i] + cs[1][i] + cs[2][i] + cs[3][i];
}

// ---------------------------------------------------------------- K3: thal + pbias + b_gate -> add8[8]
__global__ void k_thal(const float* __restrict__ partials,
                       const float* __restrict__ Wth, const float* __restrict__ bth,
                       const float* __restrict__ Wpm, const float* __restrict__ bpm,
                       const float* __restrict__ bgate, float* __restrict__ add8)
{
  __shared__ float cm[768];
  __shared__ float th[8];
  const int t = threadIdx.x;
  float s = 0.f;
  #pragma unroll 8
  for (int b = 0; b < 512; b++) s += partials[(size_t)b * 768 + t];
  cm[t] = s * (1.0f / 16384.0f);
  __syncthreads();
  if (t < 256) {
    int e = t >> 5, l = t & 31;
    float ps = 0.f;
    for (int c = l; c < 768; c += 32) ps = fmaf(cm[c], Wth[(size_t)c * 8 + e], ps);
    #pragma unroll
    for (int off = 16; off; off >>= 1) ps += __shfl_xor(ps, off);
    if (l == 0) th[e] = ps + bth[e];
  }
  __syncthreads();
  if (t < 8) {
    const float TR[5] = {0.6f, 0.6f, 0.5f, 0.5f, 0.4f};
    float pb = bpm[t];
    #pragma unroll
    for (int i = 0; i < 5; i++) pb = fmaf(TR[i], Wpm[i * 8 + t], pb);
    add8[t] = th[t] + pb + bgate[t];
  }
}

// ---------------------------------------------------------------- K4: gate top-2 + softmax + counts
__global__ __launch_bounds__(256) void k_route(const float* __restrict__ glog,
                                               const float* __restrict__ add8,
                                               float* __restrict__ rw,
                                               unsigned char* __restrict__ re,
                                               int* __restrict__ counts)
{
  __shared__ float a8[8];
  __shared__ int lc[8];
  const int t = threadIdx.x;
  if (t < 8) { a8[t] = add8[t]; lc[t] = 0; }
  __syncthreads();
  const int row = blockIdx.x * 256 + t;
  const float4* gp = reinterpret_cast<const float4*>(glog + (size_t)row * 8);
  float4 g0 = gp[0], g1 = gp[1];
  float l[8] = { g0.x + a8[0], g0.y + a8[1], g0.z + a8[2], g0.w + a8[3],
                 g1.x + a8[4], g1.y + a8[5], g1.z + a8[6], g1.w + a8[7] };
  float v0 = l[0], v1 = -3.4e38f; int i0 = 0, i1 = 0;
  #pragma unroll
  for (int e = 1; e < 8; e++) {
    if (l[e] > v0)      { v1 = v0; i1 = i0; v0 = l[e]; i0 = e; }
    else if (l[e] > v1) { v1 = l[e]; i1 = e; }
  }
  float ex = expf(v1 - v0);
  float inv = 1.0f / (1.0f + ex);
  rw[row * 2] = inv; rw[row * 2 + 1] = ex * inv;
  re[row * 2] = (unsigned char)i0; re[row * 2 + 1] = (unsigned char)i1;
  atomicAdd(&lc[i0], 1); atomicAdd(&lc[i1], 1);
  __syncthreads();
  if (t < 8) atomicAdd(&counts[t], lc[t]);
}

// ---------------------------------------------------------------- K4b: prefix sums -> meta
// meta layout: [0..8]=offs, [9..17]=tile_start, [18]=total_tiles, [19..26]=cursors
__global__ void k_prefix(const int* __restrict__ counts, int* __restrict__ meta)
{
  if (threadIdx.x == 0) {
    int o = 0, tt = 0;
    for (int e = 0; e < 8; e++) {
      meta[e] = o; meta[9 + e] = tt; meta[19 + e] = o;
      o += counts[e]; tt += (counts[e] + 127) >> 7;
    }
    meta[8] = o; meta[17] = tt; meta[18] = tt;
  }
}

// ---------------------------------------------------------------- K4c: bucket-scatter rows into per-expert segments (+ inverse)
__global__ __launch_bounds__(256) void k_scatter(const unsigned char* __restrict__ re,
                                                 int* __restrict__ meta,
                                                 int* __restrict__ perm,
                                                 int* __restrict__ inv)
{
  __shared__ int lc[8], base[8];
  const int t = threadIdx.x;
  if (t < 8) lc[t] = 0;
  __syncthreads();
  const int row = blockIdx.x * 256 + t;
  const int e0 = re[row * 2], e1 = re[row * 2 + 1];
  const int p0 = atomicAdd(&lc[e0], 1);
  const int p1 = atomicAdd(&lc[e1], 1);
  __syncthreads();
  if (t < 8) base[t] = atomicAdd(&meta[19 + t], lc[t]);
  __syncthreads();
  const int s0 = base[e0] + p0;
  const int s1 = base[e1] + p1;
  perm[s0] = row * 2;     inv[row * 2]     = s0;
  perm[s1] = row * 2 + 1; inv[row * 2 + 1] = s1;
}

// ---------------------------------------------------------------- K5: routed expert GEMM, bf16 MFMA, 128x128 tiles
// double-buffered global_load_lds, counted vmcnt, raw barriers; grid (nb, tile) for L3 A-row sharing
__global__ __launch_bounds__(256) void k_expert(const unsigned short* __restrict__ attb,
                                                const unsigned short* __restrict__ Wt,
                                                const float* __restrict__ bexp,
                                                const float* __restrict__ rw,
                                                const int* __restrict__ perm,
                                                const int* __restrict__ meta,
                                                ushort_t* __restrict__ ctxP)
{
  if ((int)blockIdx.y >= meta[18]) return;
  __shared__ __align__(16) ushort_t sst[2][2][8192];   // [buf][A/B][128x64]; sst[0] reused as C tile
  __shared__ int rid[128];
  __shared__ float gws[128];
  __shared__ float bxs[128];

  const int* tst = meta + 9;
  const int tb = blockIdx.y;
  int e = 0;
  #pragma unroll
  for (int i = 1; i < 8; i++) if (tb >= tst[i]) e = i;
  const int tix  = tb - tst[e];
  const int off  = meta[e];
  const int cnt  = meta[e + 1] - off;
  const int rbase = off + tix * 128;
  const int vcnt  = min(128, cnt - tix * 128);
  const int tid = threadIdx.x;
  const int nb  = blockIdx.x * 128;

  if (tid < 128) {
    if (tid < vcnt) {
      int p = perm[rbase + tid];
      rid[tid] = p >> 1; gws[tid] = rw[p];
    } else {
      rid[tid] = 0; gws[tid] = 0.f;
    }
    bxs[tid] = bexp[(size_t)e * HID + nb + tid];
  }
  __syncthreads();

  const int lane = tid & 63, w = tid >> 6;
  const int m0 = (w >> 1) * 64, n0 = (w & 1) * 64;
  const int l15 = lane & 15, g = lane >> 4;
  const unsigned short* wbase = Wt + ((size_t)e * HID + nb) * HID;

#define ESTAGE(kb, b)                                                          \
  { _Pragma("unroll")                                                          \
    for (int i = 0; i < 4; i++) {                                              \
      int id_ = i * 256 + tid; int r_ = id_ >> 3, c_ = id_ & 7;                \
      int sc_ = (c_ ^ (r_ & 7)) * 8;                                           \
      GLD16(attb + (size_t)rid[r_] * HID + (kb) + sc_, &sst[b][0][(i * 256 + w * 64) * 8]); \
      GLD16(wbase + (size_t)r_ * HID + (kb) + sc_,     &sst[b][1][(i * 256 + w * 64) * 8]); \
    } }

  f32x4 acc[4][4];
  #pragma unroll
  for (int i = 0; i < 4; i++)
    #pragma unroll
    for (int j = 0; j < 4; j++) acc[i][j] = (f32x4){0.f, 0.f, 0.f, 0.f};

  ESTAGE(0, 0);
  for (int t = 0; t < 12; t++) {
    const int cb = t & 1;
    if (t < 11) {
      ESTAGE((t + 1) * 64, cb ^ 1);
      asm volatile("s_waitcnt vmcnt(8)" ::: "memory");   // tile-t staged; t+1 stays in flight
    } else {
      asm volatile("s_waitcnt vmcnt(0)" ::: "memory");
    }
    __builtin_amdgcn_s_barrier();
    const ushort_t* As = &sst[cb][0][0];
    const ushort_t* Bs = &sst[cb][1][0];
    #pragma unroll
    for (int ks = 0; ks < 2; ks++) {
      bf16x8 af[4], bfr[4];
      #pragma unroll
      for (int i = 0; i < 4; i++) {
        int ca = (((4 * ks + g) ^ (l15 & 7)) * 8);
        af[i]  = *reinterpret_cast<const bf16x8*>(As + (m0 + 16 * i + l15) * 64 + ca);
        bfr[i] = *reinterpret_cast<const bf16x8*>(Bs + (n0 + 16 * i + l15) * 64 + ca);
      }
      #pragma unroll
      for (int i = 0; i < 4; i++)
        #pragma unroll
        for (int j = 0; j < 4; j++)
          acc[i][j] = __builtin_amdgcn_mfma_f32_16x16x32_bf16(af[i], bfr[j], acc[i][j], 0, 0, 0);
    }
    __builtin_amdgcn_s_barrier();
  }
#undef ESTAGE

  // epilogue: stage C tile (gw * (acc + bias) -> bf16) in LDS, then contiguous slot-row stores.
  unsigned short* Cs = &sst[0][0][0];    // [128][128] bf16 = 32 KB
  __syncthreads();
  #pragma unroll
  for (int i = 0; i < 4; i++) {
    #pragma unroll
    for (int q = 0; q < 4; q++) {
      int m = m0 + 16 * i + g * 4 + q;
      float gwv = gws[m];
      #pragma unroll
      for (int j = 0; j < 4; j++) {
        int n = n0 + 16 * j + l15;
        Cs[m * 128 + n] = bf16_rne(gwv * (acc[i][j][q] + bxs[n]));
      }
    }
  }
  __syncthreads();
  #pragma unroll
  for (int c = 0; c < 8; c++) {
    int r = w * 32 + c * 4 + (lane >> 4);     // 4 rows/instr, each 256 B contiguous
    if (r < vcnt) {
      uint4 v = *reinterpret_cast<const uint4*>(Cs + r * 128 + l15 * 8);
      *reinterpret_cast<uint4*>(ctxP + (size_t)(rbase + r) * HID + nb + l15 * 8) = v;
    }
  }
}

// ---------------------------------------------------------------- K6: out = (ctxP[inv0] + ctxP[inv1]) @ W_out + b_out
__global__ __launch_bounds__(256) void k_out(const ushort_t* __restrict__ ctxP,
                                             const int* __restrict__ inv,
                                             const float* __restrict__ Wout,
                                             const float* __restrict__ bout,
                                             float* __restrict__ out)
{
  __shared__ float wT[10][768];
  const int t = threadIdx.x, lane = t & 63, w = t >> 6;
  for (int i = t; i < 7680; i += 256) { int cl = i / 768, d = i - cl * 768; wT[cl][d] = Wout[(size_t)d * 10 + cl]; }
  __syncthreads();
  for (int rr = 0; rr < 8; ++rr) {
    const int row = blockIdx.x * 32 + rr * 4 + w;
    const int s0 = inv[row * 2], s1 = inv[row * 2 + 1];
    const ushort_t* p0 = ctxP + (size_t)s0 * HID;
    const ushort_t* p1 = ctxP + (size_t)s1 * HID;
    float cd[12];
    #pragma unroll
    for (int j = 0; j < 12; j++)
      cd[j] = bf16_to_f(p0[lane + 64 * j]) + bf16_to_f(p1[lane + 64 * j]);
    float p[10];
    #pragma unroll
    for (int cl = 0; cl < 10; cl++) {
      float ps = 0.f;
      #pragma unroll
      for (int j = 0; j < 12; j++) ps = fmaf(cd[j], wT[cl][lane + 64 * j], ps);
      #pragma unroll
      for (int off = 32; off; off >>= 1) ps += __shfl_xor(ps, off);
      p[cl] = ps;
    }
    if (lane == 0) {
      #pragma unroll
      for (int cl = 0; cl < 10; cl++) out[(size_t)row * 10 + cl] = p[cl] + bout[cl];
    }
  }
}

// ---------------------------------------------------------------- launch
extern "C" void kernel_launch(void* const* d_in, const int* in_sizes, int n_in,
                              void* d_out, int out_size, void* d_ws, size_t ws_size,
                              hipStream_t stream)
{
  const float* x     = (const float*)d_in[0];
  const float* W_in  = (const float*)d_in[1];
  const float* b_in  = (const float*)d_in[2];
  const float* W_ph  = (const float*)d_in[3];
  const float* b_ph  = (const float*)d_in[4];
  const float* W_g   = (const float*)d_in[5];
  const float* b_g   = (const float*)d_in[6];
  const float* W_exp = (const float*)d_in[7];
  const float* b_exp = (const float*)d_in[8];
  const float* W_th  = (const float*)d_in[9];
  const float* b_th  = (const float*)d_in[10];
  const float* W_pm  = (const float*)d_in[11];
  const float* b_pm  = (const float*)d_in[12];
  const float* W_out = (const float*)d_in[13];
  const float* b_out = (const float*)d_in[14];
  float* out = (float*)d_out;

  char* ws = (char*)d_ws;
  size_t off = 0;
  float* enh = (float*)(ws + off); off += (size_t)BATCH * HID * 4;     // proj/enh; later ctxP (bf16, 32768 rows)
  char*  r1  = ws + off;           off += (size_t)2 * BATCH * KT13 * 64 * 2;  // 54.5 MB multi-use region
  // r1 phase 1 (packA..proj3): Ahi | Alo
  ushort_t* Ahi = (ushort_t*)r1;
  ushort_t* Alo = Ahi + (size_t)BATCH * KT13 * 64;
  // r1 phase 2 (wtrans..expert): attb | Wt   (Ahi/Alo dead after k_proj3)
  __hip_bfloat16* attb = (__hip_bfloat16*)r1;
  __hip_bfloat16* Wt   = (__hip_bfloat16*)(r1 + (size_t)BATCH * HID * 2);
  float* glog     = (float*)(ws + off); off += (size_t)BATCH * 8 * 4;
  float* partials = (float*)(ws + off); off += (size_t)512 * 768 * 4;
  float* pm       = (float*)(ws + off); off += (size_t)12 * BATCH * 4;
  float* add8     = (float*)(ws + off); off += 256;
  float* rw       = (float*)(ws + off); off += (size_t)BATCH * 2 * 4;
  unsigned char* re = (unsigned char*)(ws + off); off += (size_t)BATCH * 2;
  int* counts = (int*)(ws + off); off += 256;
  int* meta   = (int*)(ws + off); off += 256;
  int* perm   = (int*)(ws + off); off += (size_t)BATCH * 2 * 4;
  int* invp   = (int*)(ws + off); off += (size_t)BATCH * 2 * 4;
  ushort_t* Bhi = (ushort_t*)(ws + off); off += (size_t)KT13 * 64 * HID * 2;
  ushort_t* Blo = (ushort_t*)(ws + off); off += (size_t)KT13 * 64 * HID * 2;
  // permuted bf16 context (32768 slots x 768) reuses the enh region (enh dead after k_attend)
  ushort_t* ctxP = (ushort_t*)enh;                                      // 50.3 MB, fits exactly

  hipMemsetAsync(counts, 0, 32, stream);
  k_packB <<<dim3(13, 6),     256, 0, stream>>>(W_in, Bhi, Blo);
  k_packA <<<dim3(13, 128),   256, 0, stream>>>(x, Ahi, Alo);
  k_proj3 <<<768,             256, 0, stream>>>(Ahi, Alo, Bhi, Blo, b_in, enh, pm);
  k_wtrans<<<dim3(24, 24, 8), 256, 0, stream>>>(W_exp, Wt);            // after proj3: Wt aliases Alo
  k_phasor<<<dim3(6, 128),    256, 0, stream>>>(pm, W_ph, b_ph, enh);
  k_attend<<<512,             256, 0, stream>>>(enh, W_g, attb, glog, partials);
  k_thal  <<<1,               768, 0, stream>>>(partials, W_th, b_th, W_pm, b_pm, b_g, add8);
  k_route <<<64,              256, 0, stream>>>(glog, add8, rw, re, counts);
  k_prefix<<<1,                64, 0, stream>>>(counts, meta);
  k_scatter<<<64,             256, 0, stream>>>(re, meta, perm, invp);
  k_expert<<<dim3(6, 264),    256, 0, stream>>>((const unsigned short*)attb, (const unsigned short*)Wt,
                                                b_exp, rw, perm, meta, ctxP);
  k_out   <<<512,             256, 0, stream>>>(ctxP, invp, W_out, b_out, out);
}

// Round 8
// 334.730 us; speedup vs baseline: 1.3893x; 1.3893x over previous
//
#include <hip/hip_runtime.h>
#include <hip/hip_bf16.h>
#include <cstddef>

// Problem constants
#define BATCH 16384
#define IND   784
#define HID   768
#define NEXP  8
#define KT13  13          // ceil(784/64) K-tiles, padded to 832

typedef short bf16x8 __attribute__((ext_vector_type(8)));
typedef float f32x4  __attribute__((ext_vector_type(4)));
typedef unsigned short ushort_t;

#define GLD16(g, l)                                                            \
  __builtin_amdgcn_global_load_lds(                                            \
      (const __attribute__((address_space(1))) unsigned int*)(g),              \
      (__attribute__((address_space(3))) unsigned int*)(l), 16, 0, 0)

// ---------------------------------------------------------------- K0: W_exp [e][h][d] f32 -> Wt [e][d][h] bf16
__global__ __launch_bounds__(256) void k_wtrans(const float* __restrict__ Wexp,
                                                __hip_bfloat16* __restrict__ Wt)
{
  __shared__ float tile[32][33];
  const int e = blockIdx.z;
  const int h0 = blockIdx.x * 32, d0 = blockIdx.y * 32;
  const int tx = threadIdx.x & 31, ty = threadIdx.x >> 5;   // 32 x 8
  const float* src = Wexp + ((size_t)e * HID + h0) * HID + d0;
  #pragma unroll
  for (int i = 0; i < 4; i++)
    tile[ty + 8 * i][tx] = src[(size_t)(ty + 8 * i) * HID + tx];
  __syncthreads();
  __hip_bfloat16* dst = Wt + ((size_t)e * HID + d0) * HID + h0;
  #pragma unroll
  for (int i = 0; i < 4; i++)
    dst[(size_t)(ty + 8 * i) * HID + tx] = __float2bfloat16(tile[tx][ty + 8 * i]);
}

// ---------------------------------------------------------------- helpers: bf16 split
__device__ inline ushort_t bf16_rne(float f) {
  union { float f; unsigned u; } v; v.f = f;
  unsigned r = v.u + 0x7fffu + ((v.u >> 16) & 1u);
  return (ushort_t)(r >> 16);
}
__device__ inline float bf16_to_f(ushort_t h) {
  union { unsigned u; float f; } v; v.u = ((unsigned)h) << 16;
  return v.f;
}

// ---------------------------------------------------------------- K0a: pack x -> swizzled bf16 hi/lo tiles [mt][kt] 128x64
__global__ __launch_bounds__(256) void k_packA(const float* __restrict__ x,
                                               ushort_t* __restrict__ Ahi,
                                               ushort_t* __restrict__ Alo)
{
  const int kt = blockIdx.x, mt = blockIdx.y;
  const size_t tbase = ((size_t)mt * KT13 + kt) * 8192;
  const int kb = kt * 64;
  #pragma unroll
  for (int i = 0; i < 4; i++) {
    int id = i * 256 + threadIdx.x;             // 1024 chunks of 8
    int r = id >> 3, c = id & 7;
    int row = mt * 128 + r;
    int k0 = kb + c * 8;
    float v[8];
    if (k0 + 8 <= IND) {
      const float4* p = reinterpret_cast<const float4*>(x + (size_t)row * IND + k0);
      float4 a = p[0], b = p[1];
      v[0] = a.x; v[1] = a.y; v[2] = a.z; v[3] = a.w;
      v[4] = b.x; v[5] = b.y; v[6] = b.z; v[7] = b.w;
    } else {
      #pragma unroll
      for (int j = 0; j < 8; j++) v[j] = (k0 + j < IND) ? x[(size_t)row * IND + k0 + j] : 0.f;
    }
    ushort_t hi[8], lo[8];
    #pragma unroll
    for (int j = 0; j < 8; j++) {
      hi[j] = bf16_rne(v[j]);
      lo[j] = bf16_rne(v[j] - bf16_to_f(hi[j]));
    }
    size_t dst = tbase + (size_t)r * 64 + ((c ^ (r & 7)) * 8);
    *reinterpret_cast<uint4*>(Ahi + dst) = *reinterpret_cast<uint4*>(hi);
    *reinterpret_cast<uint4*>(Alo + dst) = *reinterpret_cast<uint4*>(lo);
  }
}

// ---------------------------------------------------------------- K0b: pack W_in^T -> swizzled bf16 hi/lo tiles [nt][kt] 128x64
__global__ __launch_bounds__(256) void k_packB(const float* __restrict__ W,
                                               ushort_t* __restrict__ Bhi,
                                               ushort_t* __restrict__ Blo)
{
  const int kt = blockIdx.x, nt = blockIdx.y;
  const size_t tbase = ((size_t)nt * KT13 + kt) * 8192;
  const int kb = kt * 64;
  #pragma unroll
  for (int i = 0; i < 4; i++) {
    int id = i * 256 + threadIdx.x;
    int r = id >> 3, c = id & 7;                 // r = output col index within tile
    int n = nt * 128 + r;
    int k0 = kb + c * 8;
    float v[8];
    #pragma unroll
    for (int j = 0; j < 8; j++)
      v[j] = (k0 + j < IND) ? W[(size_t)(k0 + j) * HID + n] : 0.f;
    ushort_t hi[8], lo[8];
    #pragma unroll
    for (int j = 0; j < 8; j++) {
      hi[j] = bf16_rne(v[j]);
      lo[j] = bf16_rne(v[j] - bf16_to_f(hi[j]));
    }
    size_t dst = tbase + (size_t)r * 64 + ((c ^ (r & 7)) * 8);
    *reinterpret_cast<uint4*>(Bhi + dst) = *reinterpret_cast<uint4*>(hi);
    *reinterpret_cast<uint4*>(Blo + dst) = *reinterpret_cast<uint4*>(lo);
  }
}

// ---------------------------------------------------------------- K1: proj = x @ W_in + b_in  (split-bf16 3-pass MFMA)
// R1-verified GLD16 staging; XCD-swizzled 1D grid; pm row-sum epilogue
__global__ __launch_bounds__(256, 2) void k_proj2(const ushort_t* __restrict__ Ahi,
                                                  const ushort_t* __restrict__ Alo,
                                                  const ushort_t* __restrict__ Bhi,
                                                  const ushort_t* __restrict__ Blo,
                                                  const float* __restrict__ bias,
                                                  float* __restrict__ out,
                                                  float* __restrict__ pm)
{
  __shared__ __align__(16) ushort_t lds[4 * 8192];   // Ahi | Alo | Bhi | Blo, each 128x64 swizzled
  // bijective XCD swizzle: 768 = 8 XCDs x 96; each XCD gets 16 mt x 6 nt
  const int bid = blockIdx.x;
  const int sid = (bid & 7) * 96 + (bid >> 3);
  const int mt = sid / 6, nt = sid - 6 * mt;
  const int tid = threadIdx.x, lane = tid & 63, w = tid >> 6;
  const int m0 = (w >> 1) * 64, n0 = (w & 1) * 64;
  const int l15 = lane & 15, g = lane >> 4;

  f32x4 acc[4][4];
  #pragma unroll
  for (int i = 0; i < 4; i++)
    #pragma unroll
    for (int j = 0; j < 4; j++) acc[i][j] = (f32x4){0.f, 0.f, 0.f, 0.f};

  const size_t abase = (size_t)mt * KT13 * 8192;
  const size_t bbase = (size_t)nt * KT13 * 8192;

  for (int kt = 0; kt < KT13; kt++) {
    __syncthreads();
    const ushort_t* srcs[4] = { Ahi + abase + (size_t)kt * 8192,
                                Alo + abase + (size_t)kt * 8192,
                                Bhi + bbase + (size_t)kt * 8192,
                                Blo + bbase + (size_t)kt * 8192 };
    #pragma unroll
    for (int buf = 0; buf < 4; buf++) {
      #pragma unroll
      for (int i = 0; i < 4; i++) {
        int off = w * 2048 + i * 512 + lane * 8;   // elements; lane*16B matches HW lane scatter
        GLD16(srcs[buf] + off, &lds[buf * 8192 + w * 2048 + i * 512]);
      }
    }
    asm volatile("s_waitcnt vmcnt(0)");
    __syncthreads();
    #pragma unroll
    for (int ks = 0; ks < 2; ks++) {
      bf16x8 ah[4], al[4], bh[4], bl[4];
      #pragma unroll
      for (int i = 0; i < 4; i++) {
        int ca = ((4 * ks + g) ^ (l15 & 7)) * 8;
        int ra = m0 + 16 * i + l15;
        ah[i] = *reinterpret_cast<const bf16x8*>(&lds[0 * 8192 + ra * 64 + ca]);
        al[i] = *reinterpret_cast<const bf16x8*>(&lds[1 * 8192 + ra * 64 + ca]);
        int rb = n0 + 16 * i + l15;
        bh[i] = *reinterpret_cast<const bf16x8*>(&lds[2 * 8192 + rb * 64 + ca]);
        bl[i] = *reinterpret_cast<const bf16x8*>(&lds[3 * 8192 + rb * 64 + ca]);
      }
      #pragma unroll
      for (int i = 0; i < 4; i++)
        #pragma unroll
        for (int j = 0; j < 4; j++) {
          acc[i][j] = __builtin_amdgcn_mfma_f32_16x16x32_bf16(ah[i], bh[j], acc[i][j], 0, 0, 0);
          acc[i][j] = __builtin_amdgcn_mfma_f32_16x16x32_bf16(ah[i], bl[j], acc[i][j], 0, 0, 0);
          acc[i][j] = __builtin_amdgcn_mfma_f32_16x16x32_bf16(al[i], bh[j], acc[i][j], 0, 0, 0);
        }
    }
  }
  // epilogue: C layout col=lane&15, row=(lane>>4)*4+reg
  float bl[4];
  #pragma unroll
  for (int j = 0; j < 4; j++) bl[j] = bias[nt * 128 + n0 + 16 * j + l15];
  #pragma unroll
  for (int i = 0; i < 4; i++) {
    #pragma unroll
    for (int q = 0; q < 4; q++) {
      int m = mt * 128 + m0 + 16 * i + g * 4 + q;
      #pragma unroll
      for (int j = 0; j < 4; j++) {
        int n = nt * 128 + n0 + 16 * j + l15;
        out[(size_t)m * HID + n] = acc[i][j][q] + bl[j];
      }
    }
  }
  // deterministic row-sum partials for mean: 12 slots/row (6 nt x 2 wave-halves)
  const float blsum = bl[0] + bl[1] + bl[2] + bl[3];
  const size_t pslot = (size_t)(nt * 2 + (w & 1)) * BATCH;
  #pragma unroll
  for (int i = 0; i < 4; i++) {
    #pragma unroll
    for (int q = 0; q < 4; q++) {
      float s = acc[i][0][q] + acc[i][1][q] + acc[i][2][q] + acc[i][3][q] + blsum;
      s += __shfl_xor(s, 1); s += __shfl_xor(s, 2);
      s += __shfl_xor(s, 4); s += __shfl_xor(s, 8);
      if (l15 == 0)
        pm[pslot + mt * 128 + m0 + 16 * i + g * 4 + q] = s;
    }
  }
}

// ---------------------------------------------------------------- K1c: enh = proj + feats @ W_ph + b_ph  (in place; means fused)
__global__ __launch_bounds__(256) void k_phasor(const float* __restrict__ pm,
                                                const float* __restrict__ Wph,
                                                const float* __restrict__ bph,
                                                float* __restrict__ enh)
{
  __shared__ float Fs[64][132];   // [k][m] transposed feats
  __shared__ float Ws[64][128];   // [k][n]
  __shared__ float mlds[128];
  const int t  = threadIdx.x;
  const int bm = blockIdx.y * 128, bn = blockIdx.x * 128;
  if (t < 128) {
    float s = 0.f;
    #pragma unroll
    for (int k = 0; k < 12; k++) s += pm[(size_t)k * BATCH + bm + t];
    mlds[t] = s * (1.0f / 768.0f);
  }
  __syncthreads();
  {
    const int r = t >> 1;
    const float mn = mlds[r];
    if ((t & 1) == 0) {
      #pragma unroll
      for (int j = 0; j < 32; j++) Fs[j][r] = sinf(mn * (7.0f * (j + 1)));
    } else {
      #pragma unroll
      for (int j = 0; j < 32; j++) Fs[32 + j][r] = cosf(mn * (7.0f * (j + 1)));
    }
  }
  #pragma unroll
  for (int i = 0; i < 8; i++) {
    int f4 = i * 256 + t;
    int k = f4 >> 5, n4 = (f4 & 31) * 4;
    *reinterpret_cast<float4*>(&Ws[k][n4]) =
        *reinterpret_cast<const float4*>(Wph + (size_t)k * HID + bn + n4);
  }
  __syncthreads();

  const int m0 = (t >> 4) * 8, n0 = (t & 15) * 8;
  float acc[8][8];
  #pragma unroll
  for (int i = 0; i < 8; i++)
    #pragma unroll
    for (int j = 0; j < 8; j++) acc[i][j] = 0.f;
  #pragma unroll 4
  for (int k = 0; k < 64; k++) {
    float a[8], b[8];
    *reinterpret_cast<float4*>(&a[0]) = *reinterpret_cast<const float4*>(&Fs[k][m0]);
    *reinterpret_cast<float4*>(&a[4]) = *reinterpret_cast<const float4*>(&Fs[k][m0 + 4]);
    *reinterpret_cast<float4*>(&b[0]) = *reinterpret_cast<const float4*>(&Ws[k][n0]);
    *reinterpret_cast<float4*>(&b[4]) = *reinterpret_cast<const float4*>(&Ws[k][n0 + 4]);
    #pragma unroll
    for (int i = 0; i < 8; i++)
      #pragma unroll
      for (int j = 0; j < 8; j++) acc[i][j] = fmaf(a[i], b[j], acc[i][j]);
  }
  float bl[8];
  #pragma unroll
  for (int j = 0; j < 8; j++) bl[j] = bph[bn + n0 + j];
  #pragma unroll
  for (int i = 0; i < 8; i++) {
    float* rowp = enh + (size_t)(bm + m0 + i) * HID + bn + n0;
    float4 p0 = *reinterpret_cast<float4*>(rowp);
    float4 p1 = *reinterpret_cast<float4*>(rowp + 4);
    p0.x += acc[i][0] + bl[0]; p0.y += acc[i][1] + bl[1];
    p0.z += acc[i][2] + bl[2]; p0.w += acc[i][3] + bl[3];
    p1.x += acc[i][4] + bl[4]; p1.y += acc[i][5] + bl[5];
    p1.z += acc[i][6] + bl[6]; p1.w += acc[i][7] + bl[7];
    *reinterpret_cast<float4*>(rowp)     = p0;
    *reinterpret_cast<float4*>(rowp + 4) = p1;
  }
}

// ---------------------------------------------------------------- K2: top-5 gains, attended(bf16), gate partials, colsum partials
__global__ __launch_bounds__(256) void k_attend(const float* __restrict__ enh,
                                                const float* __restrict__ Wg,
                                                __hip_bfloat16* __restrict__ attb,
                                                float* __restrict__ glog,
                                                float* __restrict__ partials)
{
  __shared__ float WgT[8][768];
  __shared__ float cs[4][768];
  const int t = threadIdx.x, lane = t & 63, w = t >> 6;
  for (int i = t; i < 768 * 8; i += 256) { int c = i >> 3, e = i & 7; WgT[e][c] = Wg[i]; }
  for (int i = t; i < 4 * 768; i += 256) cs[i / 768][i % 768] = 0.f;
  __syncthreads();

  for (int rr = 0; rr < 8; ++rr) {
    const int row = blockIdx.x * 32 + rr * 4 + w;
    const float* er = enh + (size_t)row * HID;
    float o[12], s[12];
    #pragma unroll
    for (int j = 0; j < 12; j++) { o[j] = er[lane + 64 * j]; s[j] = o[j]; }

    int wc[5];
    #pragma unroll
    for (int k = 0; k < 5; k++) {
      float v = -3.4e38f; int c = 0x7fffffff;
      #pragma unroll
      for (int j = 0; j < 12; j++)
        if (s[j] > v) { v = s[j]; c = lane + 64 * j; }          // ascending j: low idx on tie
      #pragma unroll
      for (int off = 32; off; off >>= 1) {
        float ov = __shfl_xor(v, off); int oc = __shfl_xor(c, off);
        if (ov > v || (ov == v && oc < c)) { v = ov; c = oc; }  // jax tie rule: lower index
      }
      wc[k] = c;
      if (lane == (c & 63)) {
        #pragma unroll
        for (int j = 0; j < 12; j++) if (j == (c >> 6)) s[j] = -3.4e38f;
      }
    }

    float a[12];
    #pragma unroll
    for (int j = 0; j < 12; j++) a[j] = o[j];
    float wv = 1.0f;
    #pragma unroll
    for (int k = 0; k < 5; k++) {
      int c = wc[k];
      if (lane == (c & 63)) {
        #pragma unroll
        for (int j = 0; j < 12; j++) if (j == (c >> 6)) a[j] = o[j] * (1.0f + wv);
      }
      wv *= 0.7f;
    }
    #pragma unroll
    for (int j = 0; j < 12; j++)
      attb[(size_t)row * HID + lane + 64 * j] = __float2bfloat16(a[j]);
    #pragma unroll
    for (int j = 0; j < 12; j++) cs[w][lane + 64 * j] += a[j];

    float p[8];
    #pragma unroll
    for (int e = 0; e < 8; e++) p[e] = 0.f;
    #pragma unroll
    for (int j = 0; j < 12; j++) {
      int c = lane + 64 * j;
      #pragma unroll
      for (int e = 0; e < 8; e++) p[e] = fmaf(a[j], WgT[e][c], p[e]);
    }
    #pragma unroll
    for (int e = 0; e < 8; e++) {
      #pragma unroll
      for (int off = 32; off; off >>= 1) p[e] += __shfl_xor(p[e], off);
    }
    if (lane == 0) {
      #pragma unroll
      for (int e = 0; e < 8; e++) glog[(size_t)row * 8 + e] = p[e];
    }
  }
  __syncthreads();
  for (int i = t; i < 768; i += 256)
    partials[(size_t)blockIdx.x * 768 + i] = cs[0][i] + cs[1][i] + cs[2][i] + cs[3][i];
}

// ---------------------------------------------------------------- K3: thal + pbias + b_gate -> add8[8]
__global__ void k_thal(const float* __restrict__ partials,
                       const float* __restrict__ Wth, const float* __restrict__ bth,
                       const float* __restrict__ Wpm, const float* __restrict__ bpm,
                       const float* __restrict__ bgate, float* __restrict__ add8)
{
  __shared__ float cm[768];
  __shared__ float th[8];
  const int t = threadIdx.x;
  float s = 0.f;
  #pragma unroll 8
  for (int b = 0; b < 512; b++) s += partials[(size_t)b * 768 + t];
  cm[t] = s * (1.0f / 16384.0f);
  __syncthreads();
  if (t < 256) {
    int e = t >> 5, l = t & 31;
    float ps = 0.f;
    for (int c = l; c < 768; c += 32) ps = fmaf(cm[c], Wth[(size_t)c * 8 + e], ps);
    #pragma unroll
    for (int off = 16; off; off >>= 1) ps += __shfl_xor(ps, off);
    if (l == 0) th[e] = ps + bth[e];
  }
  __syncthreads();
  if (t < 8) {
    const float TR[5] = {0.6f, 0.6f, 0.5f, 0.5f, 0.4f};
    float pb = bpm[t];
    #pragma unroll
    for (int i = 0; i < 5; i++) pb = fmaf(TR[i], Wpm[i * 8 + t], pb);
    add8[t] = th[t] + pb + bgate[t];
  }
}

// ---------------------------------------------------------------- K4: gate top-2 + softmax + counts
__global__ __launch_bounds__(256) void k_route(const float* __restrict__ glog,
                                               const float* __restrict__ add8,
                                               float* __restrict__ rw,
                                               unsigned char* __restrict__ re,
                                               int* __restrict__ counts)
{
  __shared__ float a8[8];
  __shared__ int lc[8];
  const int t = threadIdx.x;
  if (t < 8) { a8[t] = add8[t]; lc[t] = 0; }
  __syncthreads();
  const int row = blockIdx.x * 256 + t;
  const float4* gp = reinterpret_cast<const float4*>(glog + (size_t)row * 8);
  float4 g0 = gp[0], g1 = gp[1];
  float l[8] = { g0.x + a8[0], g0.y + a8[1], g0.z + a8[2], g0.w + a8[3],
                 g1.x + a8[4], g1.y + a8[5], g1.z + a8[6], g1.w + a8[7] };
  float v0 = l[0], v1 = -3.4e38f; int i0 = 0, i1 = 0;
  #pragma unroll
  for (int e = 1; e < 8; e++) {
    if (l[e] > v0)      { v1 = v0; i1 = i0; v0 = l[e]; i0 = e; }
    else if (l[e] > v1) { v1 = l[e]; i1 = e; }
  }
  float ex = expf(v1 - v0);
  float inv = 1.0f / (1.0f + ex);
  rw[row * 2] = inv; rw[row * 2 + 1] = ex * inv;
  re[row * 2] = (unsigned char)i0; re[row * 2 + 1] = (unsigned char)i1;
  atomicAdd(&lc[i0], 1); atomicAdd(&lc[i1], 1);
  __syncthreads();
  if (t < 8) atomicAdd(&counts[t], lc[t]);
}

// ---------------------------------------------------------------- K4b: prefix sums -> meta
// meta layout: [0..8]=offs, [9..17]=tile_start, [18]=total_tiles, [19..26]=cursors
__global__ void k_prefix(const int* __restrict__ counts, int* __restrict__ meta)
{
  if (threadIdx.x == 0) {
    int o = 0, tt = 0;
    for (int e = 0; e < 8; e++) {
      meta[e] = o; meta[9 + e] = tt; meta[19 + e] = o;
      o += counts[e]; tt += (counts[e] + 127) >> 7;
    }
    meta[8] = o; meta[17] = tt; meta[18] = tt;
  }
}

// ---------------------------------------------------------------- K4c: bucket-scatter rows into per-expert segments (+ inverse)
__global__ __launch_bounds__(256) void k_scatter(const unsigned char* __restrict__ re,
                                                 int* __restrict__ meta,
                                                 int* __restrict__ perm,
                                                 int* __restrict__ inv)
{
  __shared__ int lc[8], base[8];
  const int t = threadIdx.x;
  if (t < 8) lc[t] = 0;
  __syncthreads();
  const int row = blockIdx.x * 256 + t;
  const int e0 = re[row * 2], e1 = re[row * 2 + 1];
  const int p0 = atomicAdd(&lc[e0], 1);
  const int p1 = atomicAdd(&lc[e1], 1);
  __syncthreads();
  if (t < 8) base[t] = atomicAdd(&meta[19 + t], lc[t]);
  __syncthreads();
  const int s0 = base[e0] + p0;
  const int s1 = base[e1] + p1;
  perm[s0] = row * 2;     inv[row * 2]     = s0;
  perm[s1] = row * 2 + 1; inv[row * 2 + 1] = s1;
}

// ---------------------------------------------------------------- K5: routed expert GEMM, bf16 MFMA, 128x128 tiles
// double-buffered global_load_lds, counted vmcnt, raw barriers; grid (nb, tile) for L3 A-row sharing
__global__ __launch_bounds__(256) void k_expert(const unsigned short* __restrict__ attb,
                                                const unsigned short* __restrict__ Wt,
                                                const float* __restrict__ bexp,
                                                const float* __restrict__ rw,
                                                const int* __restrict__ perm,
                                                const int* __restrict__ meta,
                                                ushort_t* __restrict__ ctxP)
{
  if ((int)blockIdx.y >= meta[18]) return;
  __shared__ __align__(16) ushort_t sst[2][2][8192];   // [buf][A/B][128x64]; sst[0] reused as C tile
  __shared__ int rid[128];
  __shared__ float gws[128];
  __shared__ float bxs[128];

  const int* tst = meta + 9;
  const int tb = blockIdx.y;
  int e = 0;
  #pragma unroll
  for (int i = 1; i < 8; i++) if (tb >= tst[i]) e = i;
  const int tix  = tb - tst[e];
  const int off  = meta[e];
  const int cnt  = meta[e + 1] - off;
  const int rbase = off + tix * 128;
  const int vcnt  = min(128, cnt - tix * 128);
  const int tid = threadIdx.x;
  const int nb  = blockIdx.x * 128;

  if (tid < 128) {
    if (tid < vcnt) {
      int p = perm[rbase + tid];
      rid[tid] = p >> 1; gws[tid] = rw[p];
    } else {
      rid[tid] = 0; gws[tid] = 0.f;
    }
    bxs[tid] = bexp[(size_t)e * HID + nb + tid];
  }
  __syncthreads();

  const int lane = tid & 63, w = tid >> 6;
  const int m0 = (w >> 1) * 64, n0 = (w & 1) * 64;
  const int l15 = lane & 15, g = lane >> 4;
  const unsigned short* wbase = Wt + ((size_t)e * HID + nb) * HID;

#define ESTAGE(kb, b)                                                          \
  { _Pragma("unroll")                                                          \
    for (int i = 0; i < 4; i++) {                                              \
      int id_ = i * 256 + tid; int r_ = id_ >> 3, c_ = id_ & 7;                \
      int sc_ = (c_ ^ (r_ & 7)) * 8;                                           \
      GLD16(attb + (size_t)rid[r_] * HID + (kb) + sc_, &sst[b][0][(i * 256 + w * 64) * 8]); \
      GLD16(wbase + (size_t)r_ * HID + (kb) + sc_,     &sst[b][1][(i * 256 + w * 64) * 8]); \
    } }

  f32x4 acc[4][4];
  #pragma unroll
  for (int i = 0; i < 4; i++)
    #pragma unroll
    for (int j = 0; j < 4; j++) acc[i][j] = (f32x4){0.f, 0.f, 0.f, 0.f};

  ESTAGE(0, 0);
  for (int t = 0; t < 12; t++) {
    const int cb = t & 1;
    if (t < 11) {
      ESTAGE((t + 1) * 64, cb ^ 1);
      asm volatile("s_waitcnt vmcnt(8)" ::: "memory");   // tile-t staged; t+1 stays in flight
    } else {
      asm volatile("s_waitcnt vmcnt(0)" ::: "memory");
    }
    __builtin_amdgcn_s_barrier();
    const ushort_t* As = &sst[cb][0][0];
    const ushort_t* Bs = &sst[cb][1][0];
    #pragma unroll
    for (int ks = 0; ks < 2; ks++) {
      bf16x8 af[4], bfr[4];
      #pragma unroll
      for (int i = 0; i < 4; i++) {
        int ca = (((4 * ks + g) ^ (l15 & 7)) * 8);
        af[i]  = *reinterpret_cast<const bf16x8*>(As + (m0 + 16 * i + l15) * 64 + ca);
        bfr[i] = *reinterpret_cast<const bf16x8*>(Bs + (n0 + 16 * i + l15) * 64 + ca);
      }
      #pragma unroll
      for (int i = 0; i < 4; i++)
        #pragma unroll
        for (int j = 0; j < 4; j++)
          acc[i][j] = __builtin_amdgcn_mfma_f32_16x16x32_bf16(af[i], bfr[j], acc[i][j], 0, 0, 0);
    }
    __builtin_amdgcn_s_barrier();
  }
#undef ESTAGE

  // epilogue: stage C tile (gw * (acc + bias) -> bf16) in LDS, then contiguous slot-row stores.
  unsigned short* Cs = &sst[0][0][0];    // [128][128] bf16 = 32 KB
  __syncthreads();
  #pragma unroll
  for (int i = 0; i < 4; i++) {
    #pragma unroll
    for (int q = 0; q < 4; q++) {
      int m = m0 + 16 * i + g * 4 + q;
      float gwv = gws[m];
      #pragma unroll
      for (int j = 0; j < 4; j++) {
        int n = n0 + 16 * j + l15;
        Cs[m * 128 + n] = bf16_rne(gwv * (acc[i][j][q] + bxs[n]));
      }
    }
  }
  __syncthreads();
  #pragma unroll
  for (int c = 0; c < 8; c++) {
    int r = w * 32 + c * 4 + (lane >> 4);     // 4 rows/instr, each 256 B contiguous
    if (r < vcnt) {
      uint4 v = *reinterpret_cast<const uint4*>(Cs + r * 128 + l15 * 8);
      *reinterpret_cast<uint4*>(ctxP + (size_t)(rbase + r) * HID + nb + l15 * 8) = v;
    }
  }
}

// ---------------------------------------------------------------- K6: out = (ctxP[inv0] + ctxP[inv1]) @ W_out + b_out
__global__ __launch_bounds__(256) void k_out(const ushort_t* __restrict__ ctxP,
                                             const int* __restrict__ inv,
                                             const float* __restrict__ Wout,
                                             const float* __restrict__ bout,
                                             float* __restrict__ out)
{
  __shared__ float wT[10][768];
  const int t = threadIdx.x, lane = t & 63, w = t >> 6;
  for (int i = t; i < 7680; i += 256) { int cl = i / 768, d = i - cl * 768; wT[cl][d] = Wout[(size_t)d * 10 + cl]; }
  __syncthreads();
  for (int rr = 0; rr < 8; ++rr) {
    const int row = blockIdx.x * 32 + rr * 4 + w;
    const int s0 = inv[row * 2], s1 = inv[row * 2 + 1];
    const ushort_t* p0 = ctxP + (size_t)s0 * HID;
    const ushort_t* p1 = ctxP + (size_t)s1 * HID;
    float cd[12];
    #pragma unroll
    for (int j = 0; j < 12; j++)
      cd[j] = bf16_to_f(p0[lane + 64 * j]) + bf16_to_f(p1[lane + 64 * j]);
    float p[10];
    #pragma unroll
    for (int cl = 0; cl < 10; cl++) {
      float ps = 0.f;
      #pragma unroll
      for (int j = 0; j < 12; j++) ps = fmaf(cd[j], wT[cl][lane + 64 * j], ps);
      #pragma unroll
      for (int off = 32; off; off >>= 1) ps += __shfl_xor(ps, off);
      p[cl] = ps;
    }
    if (lane == 0) {
      #pragma unroll
      for (int cl = 0; cl < 10; cl++) out[(size_t)row * 10 + cl] = p[cl] + bout[cl];
    }
  }
}

// ---------------------------------------------------------------- launch
extern "C" void kernel_launch(void* const* d_in, const int* in_sizes, int n_in,
                              void* d_out, int out_size, void* d_ws, size_t ws_size,
                              hipStream_t stream)
{
  const float* x     = (const float*)d_in[0];
  const float* W_in  = (const float*)d_in[1];
  const float* b_in  = (const float*)d_in[2];
  const float* W_ph  = (const float*)d_in[3];
  const float* b_ph  = (const float*)d_in[4];
  const float* W_g   = (const float*)d_in[5];
  const float* b_g   = (const float*)d_in[6];
  const float* W_exp = (const float*)d_in[7];
  const float* b_exp = (const float*)d_in[8];
  const float* W_th  = (const float*)d_in[9];
  const float* b_th  = (const float*)d_in[10];
  const float* W_pm  = (const float*)d_in[11];
  const float* b_pm  = (const float*)d_in[12];
  const float* W_out = (const float*)d_in[13];
  const float* b_out = (const float*)d_in[14];
  float* out = (float*)d_out;

  char* ws = (char*)d_ws;
  size_t off = 0;
  float* enh = (float*)(ws + off); off += (size_t)BATCH * HID * 4;     // proj/enh; later ctxP (bf16, 32768 rows)
  char*  r1  = ws + off;           off += (size_t)2 * BATCH * KT13 * 64 * 2;  // 54.5 MB multi-use region
  // r1 phase 1 (packA..proj2): Ahi | Alo
  ushort_t* Ahi = (ushort_t*)r1;
  ushort_t* Alo = Ahi + (size_t)BATCH * KT13 * 64;
  // r1 phase 2 (wtrans..expert): attb | Wt   (Ahi/Alo dead after k_proj2)
  __hip_bfloat16* attb = (__hip_bfloat16*)r1;
  __hip_bfloat16* Wt   = (__hip_bfloat16*)(r1 + (size_t)BATCH * HID * 2);
  float* glog     = (float*)(ws + off); off += (size_t)BATCH * 8 * 4;
  float* partials = (float*)(ws + off); off += (size_t)512 * 768 * 4;
  float* pm       = (float*)(ws + off); off += (size_t)12 * BATCH * 4;
  float* add8     = (float*)(ws + off); off += 256;
  float* rw       = (float*)(ws + off); off += (size_t)BATCH * 2 * 4;
  unsigned char* re = (unsigned char*)(ws + off); off += (size_t)BATCH * 2;
  int* counts = (int*)(ws + off); off += 256;
  int* meta   = (int*)(ws + off); off += 256;
  int* perm   = (int*)(ws + off); off += (size_t)BATCH * 2 * 4;
  int* invp   = (int*)(ws + off); off += (size_t)BATCH * 2 * 4;
  ushort_t* Bhi = (ushort_t*)(ws + off); off += (size_t)KT13 * 64 * HID * 2;
  ushort_t* Blo = (ushort_t*)(ws + off); off += (size_t)KT13 * 64 * HID * 2;
  // permuted bf16 context (32768 slots x 768) reuses the enh region (enh dead after k_attend)
  ushort_t* ctxP = (ushort_t*)enh;                                      // 50.3 MB, fits exactly

  hipMemsetAsync(counts, 0, 32, stream);
  k_packB <<<dim3(13, 6),     256, 0, stream>>>(W_in, Bhi, Blo);
  k_packA <<<dim3(13, 128),   256, 0, stream>>>(x, Ahi, Alo);
  k_proj2 <<<768,             256, 0, stream>>>(Ahi, Alo, Bhi, Blo, b_in, enh, pm);
  k_wtrans<<<dim3(24, 24, 8), 256, 0, stream>>>(W_exp, Wt);            // after proj2: Wt aliases r1 tail
  k_phasor<<<dim3(6, 128),    256, 0, stream>>>(pm, W_ph, b_ph, enh);
  k_attend<<<512,             256, 0, stream>>>(enh, W_g, attb, glog, partials);
  k_thal  <<<1,               768, 0, stream>>>(partials, W_th, b_th, W_pm, b_pm, b_g, add8);
  k_route <<<64,              256, 0, stream>>>(glog, add8, rw, re, counts);
  k_prefix<<<1,                64, 0, stream>>>(counts, meta);
  k_scatter<<<64,             256, 0, stream>>>(re, meta, perm, invp);
  k_expert<<<dim3(6, 264),    256, 0, stream>>>((const unsigned short*)attb, (const unsigned short*)Wt,
                                                b_exp, rw, perm, meta, ctxP);
  k_out   <<<512,             256, 0, stream>>>(ctxP, invp, W_out, b_out, out);
}

// Round 9
// 324.796 us; speedup vs baseline: 1.4317x; 1.0306x over previous
//
#include <hip/hip_runtime.h>
#include <hip/hip_bf16.h>
#include <cstddef>

// Problem constants
#define BATCH 16384
#define IND   784
#define HID   768
#define NEXP  8
#define KT13  13          // ceil(784/64) K-tiles, padded to 832

typedef short bf16x8 __attribute__((ext_vector_type(8)));
typedef float f32x4  __attribute__((ext_vector_type(4)));
typedef unsigned short ushort_t;

#define GLD16(g, l)                                                            \
  __builtin_amdgcn_global_load_lds(                                            \
      (const __attribute__((address_space(1))) unsigned int*)(g),              \
      (__attribute__((address_space(3))) unsigned int*)(l), 16, 0, 0)

// ---------------------------------------------------------------- K0: W_exp [e][h][d] f32 -> Wt [e][d][h] bf16
__global__ __launch_bounds__(256) void k_wtrans(const float* __restrict__ Wexp,
                                                __hip_bfloat16* __restrict__ Wt)
{
  __shared__ float tile[32][33];
  const int e = blockIdx.z;
  const int h0 = blockIdx.x * 32, d0 = blockIdx.y * 32;
  const int tx = threadIdx.x & 31, ty = threadIdx.x >> 5;   // 32 x 8
  const float* src = Wexp + ((size_t)e * HID + h0) * HID + d0;
  #pragma unroll
  for (int i = 0; i < 4; i++)
    tile[ty + 8 * i][tx] = src[(size_t)(ty + 8 * i) * HID + tx];
  __syncthreads();
  __hip_bfloat16* dst = Wt + ((size_t)e * HID + d0) * HID + h0;
  #pragma unroll
  for (int i = 0; i < 4; i++)
    dst[(size_t)(ty + 8 * i) * HID + tx] = __float2bfloat16(tile[tx][ty + 8 * i]);
}

// ---------------------------------------------------------------- helpers: bf16 split
__device__ inline ushort_t bf16_rne(float f) {
  union { float f; unsigned u; } v; v.f = f;
  unsigned r = v.u + 0x7fffu + ((v.u >> 16) & 1u);
  return (ushort_t)(r >> 16);
}
__device__ inline float bf16_to_f(ushort_t h) {
  union { unsigned u; float f; } v; v.u = ((unsigned)h) << 16;
  return v.f;
}

// ---------------------------------------------------------------- K0a: pack x -> swizzled bf16 hi/lo tiles [mt][kt] 128x64
__global__ __launch_bounds__(256) void k_packA(const float* __restrict__ x,
                                               ushort_t* __restrict__ Ahi,
                                               ushort_t* __restrict__ Alo)
{
  const int kt = blockIdx.x, mt = blockIdx.y;
  const size_t tbase = ((size_t)mt * KT13 + kt) * 8192;
  const int kb = kt * 64;
  #pragma unroll
  for (int i = 0; i < 4; i++) {
    int id = i * 256 + threadIdx.x;             // 1024 chunks of 8
    int r = id >> 3, c = id & 7;
    int row = mt * 128 + r;
    int k0 = kb + c * 8;
    float v[8];
    if (k0 + 8 <= IND) {
      const float4* p = reinterpret_cast<const float4*>(x + (size_t)row * IND + k0);
      float4 a = p[0], b = p[1];
      v[0] = a.x; v[1] = a.y; v[2] = a.z; v[3] = a.w;
      v[4] = b.x; v[5] = b.y; v[6] = b.z; v[7] = b.w;
    } else {
      #pragma unroll
      for (int j = 0; j < 8; j++) v[j] = (k0 + j < IND) ? x[(size_t)row * IND + k0 + j] : 0.f;
    }
    ushort_t hi[8], lo[8];
    #pragma unroll
    for (int j = 0; j < 8; j++) {
      hi[j] = bf16_rne(v[j]);
      lo[j] = bf16_rne(v[j] - bf16_to_f(hi[j]));
    }
    size_t dst = tbase + (size_t)r * 64 + ((c ^ (r & 7)) * 8);
    *reinterpret_cast<uint4*>(Ahi + dst) = *reinterpret_cast<uint4*>(hi);
    *reinterpret_cast<uint4*>(Alo + dst) = *reinterpret_cast<uint4*>(lo);
  }
}

// ---------------------------------------------------------------- K0b: pack W_in^T -> swizzled bf16 hi/lo tiles [nt][kt] 128x64
__global__ __launch_bounds__(256) void k_packB(const float* __restrict__ W,
                                               ushort_t* __restrict__ Bhi,
                                               ushort_t* __restrict__ Blo)
{
  const int kt = blockIdx.x, nt = blockIdx.y;
  const size_t tbase = ((size_t)nt * KT13 + kt) * 8192;
  const int kb = kt * 64;
  #pragma unroll
  for (int i = 0; i < 4; i++) {
    int id = i * 256 + threadIdx.x;
    int r = id >> 3, c = id & 7;                 // r = output col index within tile
    int n = nt * 128 + r;
    int k0 = kb + c * 8;
    float v[8];
    #pragma unroll
    for (int j = 0; j < 8; j++)
      v[j] = (k0 + j < IND) ? W[(size_t)(k0 + j) * HID + n] : 0.f;
    ushort_t hi[8], lo[8];
    #pragma unroll
    for (int j = 0; j < 8; j++) {
      hi[j] = bf16_rne(v[j]);
      lo[j] = bf16_rne(v[j] - bf16_to_f(hi[j]));
    }
    size_t dst = tbase + (size_t)r * 64 + ((c ^ (r & 7)) * 8);
    *reinterpret_cast<uint4*>(Bhi + dst) = *reinterpret_cast<uint4*>(hi);
    *reinterpret_cast<uint4*>(Blo + dst) = *reinterpret_cast<uint4*>(lo);
  }
}

// ---------------------------------------------------------------- K1: proj = x @ W_in + b_in  (split-bf16 3-pass MFMA)
// R1-verified GLD16 staging; XCD-swizzled 1D grid; pm row-sum epilogue
__global__ __launch_bounds__(256, 2) void k_proj2(const ushort_t* __restrict__ Ahi,
                                                  const ushort_t* __restrict__ Alo,
                                                  const ushort_t* __restrict__ Bhi,
                                                  const ushort_t* __restrict__ Blo,
                                                  const float* __restrict__ bias,
                                                  float* __restrict__ out,
                                                  float* __restrict__ pm)
{
  __shared__ __align__(16) ushort_t lds[4 * 8192];   // Ahi | Alo | Bhi | Blo, each 128x64 swizzled
  // bijective XCD swizzle: 768 = 8 XCDs x 96; each XCD gets 16 mt x 6 nt
  const int bid = blockIdx.x;
  const int sid = (bid & 7) * 96 + (bid >> 3);
  const int mt = sid / 6, nt = sid - 6 * mt;
  const int tid = threadIdx.x, lane = tid & 63, w = tid >> 6;
  const int m0 = (w >> 1) * 64, n0 = (w & 1) * 64;
  const int l15 = lane & 15, g = lane >> 4;

  f32x4 acc[4][4];
  #pragma unroll
  for (int i = 0; i < 4; i++)
    #pragma unroll
    for (int j = 0; j < 4; j++) acc[i][j] = (f32x4){0.f, 0.f, 0.f, 0.f};

  const size_t abase = (size_t)mt * KT13 * 8192;
  const size_t bbase = (size_t)nt * KT13 * 8192;

  for (int kt = 0; kt < KT13; kt++) {
    __syncthreads();
    const ushort_t* srcs[4] = { Ahi + abase + (size_t)kt * 8192,
                                Alo + abase + (size_t)kt * 8192,
                                Bhi + bbase + (size_t)kt * 8192,
                                Blo + bbase + (size_t)kt * 8192 };
    #pragma unroll
    for (int buf = 0; buf < 4; buf++) {
      #pragma unroll
      for (int i = 0; i < 4; i++) {
        int off = w * 2048 + i * 512 + lane * 8;   // elements; lane*16B matches HW lane scatter
        GLD16(srcs[buf] + off, &lds[buf * 8192 + w * 2048 + i * 512]);
      }
    }
    asm volatile("s_waitcnt vmcnt(0)");
    __syncthreads();
    #pragma unroll
    for (int ks = 0; ks < 2; ks++) {
      bf16x8 ah[4], al[4], bh[4], bl[4];
      #pragma unroll
      for (int i = 0; i < 4; i++) {
        int ca = ((4 * ks + g) ^ (l15 & 7)) * 8;
        int ra = m0 + 16 * i + l15;
        ah[i] = *reinterpret_cast<const bf16x8*>(&lds[0 * 8192 + ra * 64 + ca]);
        al[i] = *reinterpret_cast<const bf16x8*>(&lds[1 * 8192 + ra * 64 + ca]);
        int rb = n0 + 16 * i + l15;
        bh[i] = *reinterpret_cast<const bf16x8*>(&lds[2 * 8192 + rb * 64 + ca]);
        bl[i] = *reinterpret_cast<const bf16x8*>(&lds[3 * 8192 + rb * 64 + ca]);
      }
      #pragma unroll
      for (int i = 0; i < 4; i++)
        #pragma unroll
        for (int j = 0; j < 4; j++) {
          acc[i][j] = __builtin_amdgcn_mfma_f32_16x16x32_bf16(ah[i], bh[j], acc[i][j], 0, 0, 0);
          acc[i][j] = __builtin_amdgcn_mfma_f32_16x16x32_bf16(ah[i], bl[j], acc[i][j], 0, 0, 0);
          acc[i][j] = __builtin_amdgcn_mfma_f32_16x16x32_bf16(al[i], bh[j], acc[i][j], 0, 0, 0);
        }
    }
  }
  // epilogue: C layout col=lane&15, row=(lane>>4)*4+reg
  float bl[4];
  #pragma unroll
  for (int j = 0; j < 4; j++) bl[j] = bias[nt * 128 + n0 + 16 * j + l15];
  #pragma unroll
  for (int i = 0; i < 4; i++) {
    #pragma unroll
    for (int q = 0; q < 4; q++) {
      int m = mt * 128 + m0 + 16 * i + g * 4 + q;
      #pragma unroll
      for (int j = 0; j < 4; j++) {
        int n = nt * 128 + n0 + 16 * j + l15;
        out[(size_t)m * HID + n] = acc[i][j][q] + bl[j];
      }
    }
  }
  // deterministic row-sum partials for mean: 12 slots/row (6 nt x 2 wave-halves)
  const float blsum = bl[0] + bl[1] + bl[2] + bl[3];
  const size_t pslot = (size_t)(nt * 2 + (w & 1)) * BATCH;
  #pragma unroll
  for (int i = 0; i < 4; i++) {
    #pragma unroll
    for (int q = 0; q < 4; q++) {
      float s = acc[i][0][q] + acc[i][1][q] + acc[i][2][q] + acc[i][3][q] + blsum;
      s += __shfl_xor(s, 1); s += __shfl_xor(s, 2);
      s += __shfl_xor(s, 4); s += __shfl_xor(s, 8);
      if (l15 == 0)
        pm[pslot + mt * 128 + m0 + 16 * i + g * 4 + q] = s;
    }
  }
}

// ---------------------------------------------------------------- K1c: enh = proj + feats @ W_ph + b_ph  (in place; means fused)
__global__ __launch_bounds__(256) void k_phasor(const float* __restrict__ pm,
                                                const float* __restrict__ Wph,
                                                const float* __restrict__ bph,
                                                float* __restrict__ enh)
{
  __shared__ float Fs[64][132];   // [k][m] transposed feats
  __shared__ float Ws[64][128];   // [k][n]
  __shared__ float mlds[128];
  const int t  = threadIdx.x;
  const int bm = blockIdx.y * 128, bn = blockIdx.x * 128;
  if (t < 128) {
    float s = 0.f;
    #pragma unroll
    for (int k = 0; k < 12; k++) s += pm[(size_t)k * BATCH + bm + t];
    mlds[t] = s * (1.0f / 768.0f);
  }
  __syncthreads();
  {
    const int r = t >> 1;
    const float mn = mlds[r];
    if ((t & 1) == 0) {
      #pragma unroll
      for (int j = 0; j < 32; j++) Fs[j][r] = sinf(mn * (7.0f * (j + 1)));
    } else {
      #pragma unroll
      for (int j = 0; j < 32; j++) Fs[32 + j][r] = cosf(mn * (7.0f * (j + 1)));
    }
  }
  #pragma unroll
  for (int i = 0; i < 8; i++) {
    int f4 = i * 256 + t;
    int k = f4 >> 5, n4 = (f4 & 31) * 4;
    *reinterpret_cast<float4*>(&Ws[k][n4]) =
        *reinterpret_cast<const float4*>(Wph + (size_t)k * HID + bn + n4);
  }
  __syncthreads();

  const int m0 = (t >> 4) * 8, n0 = (t & 15) * 8;
  float acc[8][8];
  #pragma unroll
  for (int i = 0; i < 8; i++)
    #pragma unroll
    for (int j = 0; j < 8; j++) acc[i][j] = 0.f;
  #pragma unroll 4
  for (int k = 0; k < 64; k++) {
    float a[8], b[8];
    *reinterpret_cast<float4*>(&a[0]) = *reinterpret_cast<const float4*>(&Fs[k][m0]);
    *reinterpret_cast<float4*>(&a[4]) = *reinterpret_cast<const float4*>(&Fs[k][m0 + 4]);
    *reinterpret_cast<float4*>(&b[0]) = *reinterpret_cast<const float4*>(&Ws[k][n0]);
    *reinterpret_cast<float4*>(&b[4]) = *reinterpret_cast<const float4*>(&Ws[k][n0 + 4]);
    #pragma unroll
    for (int i = 0; i < 8; i++)
      #pragma unroll
      for (int j = 0; j < 8; j++) acc[i][j] = fmaf(a[i], b[j], acc[i][j]);
  }
  float bl[8];
  #pragma unroll
  for (int j = 0; j < 8; j++) bl[j] = bph[bn + n0 + j];
  #pragma unroll
  for (int i = 0; i < 8; i++) {
    float* rowp = enh + (size_t)(bm + m0 + i) * HID + bn + n0;
    float4 p0 = *reinterpret_cast<float4*>(rowp);
    float4 p1 = *reinterpret_cast<float4*>(rowp + 4);
    p0.x += acc[i][0] + bl[0]; p0.y += acc[i][1] + bl[1];
    p0.z += acc[i][2] + bl[2]; p0.w += acc[i][3] + bl[3];
    p1.x += acc[i][4] + bl[4]; p1.y += acc[i][5] + bl[5];
    p1.z += acc[i][6] + bl[6]; p1.w += acc[i][7] + bl[7];
    *reinterpret_cast<float4*>(rowp)     = p0;
    *reinterpret_cast<float4*>(rowp + 4) = p1;
  }
}

// ---------------------------------------------------------------- K2: top-5 gains, attended(bf16), gate partials, colsum partials
__global__ __launch_bounds__(256) void k_attend(const float* __restrict__ enh,
                                                const float* __restrict__ Wg,
                                                __hip_bfloat16* __restrict__ attb,
                                                float* __restrict__ glog,
                                                float* __restrict__ partials)
{
  __shared__ float WgT[8][768];
  __shared__ float cs[4][768];
  const int t = threadIdx.x, lane = t & 63, w = t >> 6;
  for (int i = t; i < 768 * 8; i += 256) { int c = i >> 3, e = i & 7; WgT[e][c] = Wg[i]; }
  for (int i = t; i < 4 * 768; i += 256) cs[i / 768][i % 768] = 0.f;
  __syncthreads();

  for (int rr = 0; rr < 8; ++rr) {
    const int row = blockIdx.x * 32 + rr * 4 + w;
    const float* er = enh + (size_t)row * HID;
    float o[12], s[12];
    #pragma unroll
    for (int j = 0; j < 12; j++) { o[j] = er[lane + 64 * j]; s[j] = o[j]; }

    int wc[5];
    #pragma unroll
    for (int k = 0; k < 5; k++) {
      float v = -3.4e38f; int c = 0x7fffffff;
      #pragma unroll
      for (int j = 0; j < 12; j++)
        if (s[j] > v) { v = s[j]; c = lane + 64 * j; }          // ascending j: low idx on tie
      #pragma unroll
      for (int off = 32; off; off >>= 1) {
        float ov = __shfl_xor(v, off); int oc = __shfl_xor(c, off);
        if (ov > v || (ov == v && oc < c)) { v = ov; c = oc; }  // jax tie rule: lower index
      }
      wc[k] = c;
      if (lane == (c & 63)) {
        #pragma unroll
        for (int j = 0; j < 12; j++) if (j == (c >> 6)) s[j] = -3.4e38f;
      }
    }

    float a[12];
    #pragma unroll
    for (int j = 0; j < 12; j++) a[j] = o[j];
    float wv = 1.0f;
    #pragma unroll
    for (int k = 0; k < 5; k++) {
      int c = wc[k];
      if (lane == (c & 63)) {
        #pragma unroll
        for (int j = 0; j < 12; j++) if (j == (c >> 6)) a[j] = o[j] * (1.0f + wv);
      }
      wv *= 0.7f;
    }
    #pragma unroll
    for (int j = 0; j < 12; j++)
      attb[(size_t)row * HID + lane + 64 * j] = __float2bfloat16(a[j]);
    #pragma unroll
    for (int j = 0; j < 12; j++) cs[w][lane + 64 * j] += a[j];

    float p[8];
    #pragma unroll
    for (int e = 0; e < 8; e++) p[e] = 0.f;
    #pragma unroll
    for (int j = 0; j < 12; j++) {
      int c = lane + 64 * j;
      #pragma unroll
      for (int e = 0; e < 8; e++) p[e] = fmaf(a[j], WgT[e][c], p[e]);
    }
    #pragma unroll
    for (int e = 0; e < 8; e++) {
      #pragma unroll
      for (int off = 32; off; off >>= 1) p[e] += __shfl_xor(p[e], off);
    }
    if (lane == 0) {
      #pragma unroll
      for (int e = 0; e < 8; e++) glog[(size_t)row * 8 + e] = p[e];
    }
  }
  __syncthreads();
  for (int i = t; i < 768; i += 256)
    partials[(size_t)blockIdx.x * 768 + i] = cs[0][i] + cs[1][i] + cs[2][i] + cs[3][i];
}

// ---------------------------------------------------------------- K3: thal + pbias + b_gate -> add8[8]
__global__ void k_thal(const float* __restrict__ partials,
                       const float* __restrict__ Wth, const float* __restrict__ bth,
                       const float* __restrict__ Wpm, const float* __restrict__ bpm,
                       const float* __restrict__ bgate, float* __restrict__ add8)
{
  __shared__ float cm[768];
  __shared__ float th[8];
  const int t = threadIdx.x;
  float s = 0.f;
  #pragma unroll 8
  for (int b = 0; b < 512; b++) s += partials[(size_t)b * 768 + t];
  cm[t] = s * (1.0f / 16384.0f);
  __syncthreads();
  if (t < 256) {
    int e = t >> 5, l = t & 31;
    float ps = 0.f;
    for (int c = l; c < 768; c += 32) ps = fmaf(cm[c], Wth[(size_t)c * 8 + e], ps);
    #pragma unroll
    for (int off = 16; off; off >>= 1) ps += __shfl_xor(ps, off);
    if (l == 0) th[e] = ps + bth[e];
  }
  __syncthreads();
  if (t < 8) {
    const float TR[5] = {0.6f, 0.6f, 0.5f, 0.5f, 0.4f};
    float pb = bpm[t];
    #pragma unroll
    for (int i = 0; i < 5; i++) pb = fmaf(TR[i], Wpm[i * 8 + t], pb);
    add8[t] = th[t] + pb + bgate[t];
  }
}

// ---------------------------------------------------------------- K4: gate top-2 + softmax + counts
__global__ __launch_bounds__(256) void k_route(const float* __restrict__ glog,
                                               const float* __restrict__ add8,
                                               float* __restrict__ rw,
                                               unsigned char* __restrict__ re,
                                               int* __restrict__ counts)
{
  __shared__ float a8[8];
  __shared__ int lc[8];
  const int t = threadIdx.x;
  if (t < 8) { a8[t] = add8[t]; lc[t] = 0; }
  __syncthreads();
  const int row = blockIdx.x * 256 + t;
  const float4* gp = reinterpret_cast<const float4*>(glog + (size_t)row * 8);
  float4 g0 = gp[0], g1 = gp[1];
  float l[8] = { g0.x + a8[0], g0.y + a8[1], g0.z + a8[2], g0.w + a8[3],
                 g1.x + a8[4], g1.y + a8[5], g1.z + a8[6], g1.w + a8[7] };
  float v0 = l[0], v1 = -3.4e38f; int i0 = 0, i1 = 0;
  #pragma unroll
  for (int e = 1; e < 8; e++) {
    if (l[e] > v0)      { v1 = v0; i1 = i0; v0 = l[e]; i0 = e; }
    else if (l[e] > v1) { v1 = l[e]; i1 = e; }
  }
  float ex = expf(v1 - v0);
  float inv = 1.0f / (1.0f + ex);
  rw[row * 2] = inv; rw[row * 2 + 1] = ex * inv;
  re[row * 2] = (unsigned char)i0; re[row * 2 + 1] = (unsigned char)i1;
  atomicAdd(&lc[i0], 1); atomicAdd(&lc[i1], 1);
  __syncthreads();
  if (t < 8) atomicAdd(&counts[t], lc[t]);
}

// ---------------------------------------------------------------- K4b: prefix sums -> meta
// meta layout: [0..8]=offs, [9..17]=tile_start, [18]=total_tiles, [19..26]=cursors
__global__ void k_prefix(const int* __restrict__ counts, int* __restrict__ meta)
{
  if (threadIdx.x == 0) {
    int o = 0, tt = 0;
    for (int e = 0; e < 8; e++) {
      meta[e] = o; meta[9 + e] = tt; meta[19 + e] = o;
      o += counts[e]; tt += (counts[e] + 127) >> 7;
    }
    meta[8] = o; meta[17] = tt; meta[18] = tt;
  }
}

// ---------------------------------------------------------------- K4c: bucket-scatter rows into per-expert segments (+ inverse)
__global__ __launch_bounds__(256) void k_scatter(const unsigned char* __restrict__ re,
                                                 int* __restrict__ meta,
                                                 int* __restrict__ perm,
                                                 int* __restrict__ inv)
{
  __shared__ int lc[8], base[8];
  const int t = threadIdx.x;
  if (t < 8) lc[t] = 0;
  __syncthreads();
  const int row = blockIdx.x * 256 + t;
  const int e0 = re[row * 2], e1 = re[row * 2 + 1];
  const int p0 = atomicAdd(&lc[e0], 1);
  const int p1 = atomicAdd(&lc[e1], 1);
  __syncthreads();
  if (t < 8) base[t] = atomicAdd(&meta[19 + t], lc[t]);
  __syncthreads();
  const int s0 = base[e0] + p0;
  const int s1 = base[e1] + p1;
  perm[s0] = row * 2;     inv[row * 2]     = s0;
  perm[s1] = row * 2 + 1; inv[row * 2 + 1] = s1;
}

// ---------------------------------------------------------------- K5: routed expert GEMM, bf16 MFMA, 128x128 tiles
// double-buffered global_load_lds, counted vmcnt, raw barriers
// XCD-grouping swizzle: all 6 nb-blocks of a tile on the SAME XCD, nb innermost
__global__ __launch_bounds__(256) void k_expert(const unsigned short* __restrict__ attb,
                                                const unsigned short* __restrict__ Wt,
                                                const float* __restrict__ bexp,
                                                const float* __restrict__ rw,
                                                const int* __restrict__ perm,
                                                const int* __restrict__ meta,
                                                ushort_t* __restrict__ ctxP)
{
  // 1584 blocks = 8 XCDs x (33 tiles x 6 nb). Dispatcher round-robins l%8 across
  // XCDs, so xcd = l&7 is (heuristically) the XCD; its 198 blocks enumerate nb
  // innermost -> the 6 blocks sharing a tile's gathered A-rows are temporally
  // adjacent on one XCD -> A staged from that XCD's L2 after one HBM fetch.
  const int l = blockIdx.x;
  const int xcd = l & 7, idx = l >> 3;
  const int tb = xcd + 8 * (idx / 6);
  const int nb = (idx - 6 * (idx / 6)) * 128;
  if (tb >= meta[18]) return;
  __shared__ __align__(16) ushort_t sst[2][2][8192];   // [buf][A/B][128x64]; sst[0] reused as C tile
  __shared__ int rid[128];
  __shared__ float gws[128];
  __shared__ float bxs[128];

  const int* tst = meta + 9;
  int e = 0;
  #pragma unroll
  for (int i = 1; i < 8; i++) if (tb >= tst[i]) e = i;
  const int tix  = tb - tst[e];
  const int off  = meta[e];
  const int cnt  = meta[e + 1] - off;
  const int rbase = off + tix * 128;
  const int vcnt  = min(128, cnt - tix * 128);
  const int tid = threadIdx.x;

  if (tid < 128) {
    if (tid < vcnt) {
      int p = perm[rbase + tid];
      rid[tid] = p >> 1; gws[tid] = rw[p];
    } else {
      rid[tid] = 0; gws[tid] = 0.f;
    }
    bxs[tid] = bexp[(size_t)e * HID + nb + tid];
  }
  __syncthreads();

  const int lane = tid & 63, w = tid >> 6;
  const int m0 = (w >> 1) * 64, n0 = (w & 1) * 64;
  const int l15 = lane & 15, g = lane >> 4;
  const unsigned short* wbase = Wt + ((size_t)e * HID + nb) * HID;

#define ESTAGE(kb, b)                                                          \
  { _Pragma("unroll")                                                          \
    for (int i = 0; i < 4; i++) {                                              \
      int id_ = i * 256 + tid; int r_ = id_ >> 3, c_ = id_ & 7;                \
      int sc_ = (c_ ^ (r_ & 7)) * 8;                                           \
      GLD16(attb + (size_t)rid[r_] * HID + (kb) + sc_, &sst[b][0][(i * 256 + w * 64) * 8]); \
      GLD16(wbase + (size_t)r_ * HID + (kb) + sc_,     &sst[b][1][(i * 256 + w * 64) * 8]); \
    } }

  f32x4 acc[4][4];
  #pragma unroll
  for (int i = 0; i < 4; i++)
    #pragma unroll
    for (int j = 0; j < 4; j++) acc[i][j] = (f32x4){0.f, 0.f, 0.f, 0.f};

  ESTAGE(0, 0);
  for (int t = 0; t < 12; t++) {
    const int cb = t & 1;
    if (t < 11) {
      ESTAGE((t + 1) * 64, cb ^ 1);
      asm volatile("s_waitcnt vmcnt(8)" ::: "memory");   // tile-t staged; t+1 stays in flight
    } else {
      asm volatile("s_waitcnt vmcnt(0)" ::: "memory");
    }
    __builtin_amdgcn_s_barrier();
    const ushort_t* As = &sst[cb][0][0];
    const ushort_t* Bs = &sst[cb][1][0];
    #pragma unroll
    for (int ks = 0; ks < 2; ks++) {
      bf16x8 af[4], bfr[4];
      #pragma unroll
      for (int i = 0; i < 4; i++) {
        int ca = (((4 * ks + g) ^ (l15 & 7)) * 8);
        af[i]  = *reinterpret_cast<const bf16x8*>(As + (m0 + 16 * i + l15) * 64 + ca);
        bfr[i] = *reinterpret_cast<const bf16x8*>(Bs + (n0 + 16 * i + l15) * 64 + ca);
      }
      #pragma unroll
      for (int i = 0; i < 4; i++)
        #pragma unroll
        for (int j = 0; j < 4; j++)
          acc[i][j] = __builtin_amdgcn_mfma_f32_16x16x32_bf16(af[i], bfr[j], acc[i][j], 0, 0, 0);
    }
    __builtin_amdgcn_s_barrier();
  }
#undef ESTAGE

  // epilogue: stage C tile (gw * (acc + bias) -> bf16) in LDS, then contiguous slot-row stores.
  unsigned short* Cs = &sst[0][0][0];    // [128][128] bf16 = 32 KB
  __syncthreads();
  #pragma unroll
  for (int i = 0; i < 4; i++) {
    #pragma unroll
    for (int q = 0; q < 4; q++) {
      int m = m0 + 16 * i + g * 4 + q;
      float gwv = gws[m];
      #pragma unroll
      for (int j = 0; j < 4; j++) {
        int n = n0 + 16 * j + l15;
        Cs[m * 128 + n] = bf16_rne(gwv * (acc[i][j][q] + bxs[n]));
      }
    }
  }
  __syncthreads();
  #pragma unroll
  for (int c = 0; c < 8; c++) {
    int r = w * 32 + c * 4 + (lane >> 4);     // 4 rows/instr, each 256 B contiguous
    if (r < vcnt) {
      uint4 v = *reinterpret_cast<const uint4*>(Cs + r * 128 + l15 * 8);
      *reinterpret_cast<uint4*>(ctxP + (size_t)(rbase + r) * HID + nb + l15 * 8) = v;
    }
  }
}

// ---------------------------------------------------------------- K6: out = (ctxP[inv0] + ctxP[inv1]) @ W_out + b_out
__global__ __launch_bounds__(256) void k_out(const ushort_t* __restrict__ ctxP,
                                             const int* __restrict__ inv,
                                             const float* __restrict__ Wout,
                                             const float* __restrict__ bout,
                                             float* __restrict__ out)
{
  __shared__ float wT[10][768];
  const int t = threadIdx.x, lane = t & 63, w = t >> 6;
  for (int i = t; i < 7680; i += 256) { int cl = i / 768, d = i - cl * 768; wT[cl][d] = Wout[(size_t)d * 10 + cl]; }
  __syncthreads();
  for (int rr = 0; rr < 8; ++rr) {
    const int row = blockIdx.x * 32 + rr * 4 + w;
    const int s0 = inv[row * 2], s1 = inv[row * 2 + 1];
    const ushort_t* p0 = ctxP + (size_t)s0 * HID;
    const ushort_t* p1 = ctxP + (size_t)s1 * HID;
    float cd[12];
    #pragma unroll
    for (int j = 0; j < 12; j++)
      cd[j] = bf16_to_f(p0[lane + 64 * j]) + bf16_to_f(p1[lane + 64 * j]);
    float p[10];
    #pragma unroll
    for (int cl = 0; cl < 10; cl++) {
      float ps = 0.f;
      #pragma unroll
      for (int j = 0; j < 12; j++) ps = fmaf(cd[j], wT[cl][lane + 64 * j], ps);
      #pragma unroll
      for (int off = 32; off; off >>= 1) ps += __shfl_xor(ps, off);
      p[cl] = ps;
    }
    if (lane == 0) {
      #pragma unroll
      for (int cl = 0; cl < 10; cl++) out[(size_t)row * 10 + cl] = p[cl] + bout[cl];
    }
  }
}

// ---------------------------------------------------------------- launch
extern "C" void kernel_launch(void* const* d_in, const int* in_sizes, int n_in,
                              void* d_out, int out_size, void* d_ws, size_t ws_size,
                              hipStream_t stream)
{
  const float* x     = (const float*)d_in[0];
  const float* W_in  = (const float*)d_in[1];
  const float* b_in  = (const float*)d_in[2];
  const float* W_ph  = (const float*)d_in[3];
  const float* b_ph  = (const float*)d_in[4];
  const float* W_g   = (const float*)d_in[5];
  const float* b_g   = (const float*)d_in[6];
  const float* W_exp = (const float*)d_in[7];
  const float* b_exp = (const float*)d_in[8];
  const float* W_th  = (const float*)d_in[9];
  const float* b_th  = (const float*)d_in[10];
  const float* W_pm  = (const float*)d_in[11];
  const float* b_pm  = (const float*)d_in[12];
  const float* W_out = (const float*)d_in[13];
  const float* b_out = (const float*)d_in[14];
  float* out = (float*)d_out;

  char* ws = (char*)d_ws;
  size_t off = 0;
  float* enh = (float*)(ws + off); off += (size_t)BATCH * HID * 4;     // proj/enh; later ctxP (bf16, 32768 rows)
  char*  r1  = ws + off;           off += (size_t)2 * BATCH * KT13 * 64 * 2;  // 54.5 MB multi-use region
  // r1 phase 1 (packA..proj2): Ahi | Alo
  ushort_t* Ahi = (ushort_t*)r1;
  ushort_t* Alo = Ahi + (size_t)BATCH * KT13 * 64;
  // r1 phase 2 (wtrans..expert): attb | Wt   (Ahi/Alo dead after k_proj2)
  __hip_bfloat16* attb = (__hip_bfloat16*)r1;
  __hip_bfloat16* Wt   = (__hip_bfloat16*)(r1 + (size_t)BATCH * HID * 2);
  float* glog     = (float*)(ws + off); off += (size_t)BATCH * 8 * 4;
  float* partials = (float*)(ws + off); off += (size_t)512 * 768 * 4;
  float* pm       = (float*)(ws + off); off += (size_t)12 * BATCH * 4;
  float* add8     = (float*)(ws + off); off += 256;
  float* rw       = (float*)(ws + off); off += (size_t)BATCH * 2 * 4;
  unsigned char* re = (unsigned char*)(ws + off); off += (size_t)BATCH * 2;
  int* counts = (int*)(ws + off); off += 256;
  int* meta   = (int*)(ws + off); off += 256;
  int* perm   = (int*)(ws + off); off += (size_t)BATCH * 2 * 4;
  int* invp   = (int*)(ws + off); off += (size_t)BATCH * 2 * 4;
  ushort_t* Bhi = (ushort_t*)(ws + off); off += (size_t)KT13 * 64 * HID * 2;
  ushort_t* Blo = (ushort_t*)(ws + off); off += (size_t)KT13 * 64 * HID * 2;
  // permuted bf16 context (32768 slots x 768) reuses the enh region (enh dead after k_attend)
  ushort_t* ctxP = (ushort_t*)enh;                                      // 50.3 MB, fits exactly

  hipMemsetAsync(counts, 0, 32, stream);
  k_packB <<<dim3(13, 6),     256, 0, stream>>>(W_in, Bhi, Blo);
  k_packA <<<dim3(13, 128),   256, 0, stream>>>(x, Ahi, Alo);
  k_proj2 <<<768,             256, 0, stream>>>(Ahi, Alo, Bhi, Blo, b_in, enh, pm);
  k_wtrans<<<dim3(24, 24, 8), 256, 0, stream>>>(W_exp, Wt);            // after proj2: Wt aliases r1 tail
  k_phasor<<<dim3(6, 128),    256, 0, stream>>>(pm, W_ph, b_ph, enh);
  k_attend<<<512,             256, 0, stream>>>(enh, W_g, attb, glog, partials);
  k_thal  <<<1,               768, 0, stream>>>(partials, W_th, b_th, W_pm, b_pm, b_g, add8);
  k_route <<<64,              256, 0, stream>>>(glog, add8, rw, re, counts);
  k_prefix<<<1,                64, 0, stream>>>(counts, meta);
  k_scatter<<<64,             256, 0, stream>>>(re, meta, perm, invp);
  k_expert<<<1584,            256, 0, stream>>>((const unsigned short*)attb, (const unsigned short*)Wt,
                                                b_exp, rw, perm, meta, ctxP);
  k_out   <<<512,             256, 0, stream>>>(ctxP, invp, W_out, b_out, out);
}

// Round 10
// 309.019 us; speedup vs baseline: 1.5048x; 1.0511x over previous
//
#include <hip/hip_runtime.h>
#include <hip/hip_bf16.h>
#include <cstddef>

// Problem constants
#define BATCH 16384
#define IND   784
#define HID   768
#define NEXP  8
#define KT13  13          // ceil(784/64) K-tiles, padded to 832

typedef short bf16x8 __attribute__((ext_vector_type(8)));
typedef float f32x4  __attribute__((ext_vector_type(4)));
typedef unsigned short ushort_t;

#define GLD16(g, l)                                                            \
  __builtin_amdgcn_global_load_lds(                                            \
      (const __attribute__((address_space(1))) unsigned int*)(g),              \
      (__attribute__((address_space(3))) unsigned int*)(l), 16, 0, 0)

// ---------------------------------------------------------------- K0: W_exp [e][h][d] f32 -> Wt [e][d][h] bf16
__global__ __launch_bounds__(256) void k_wtrans(const float* __restrict__ Wexp,
                                                __hip_bfloat16* __restrict__ Wt)
{
  __shared__ float tile[32][33];
  const int e = blockIdx.z;
  const int h0 = blockIdx.x * 32, d0 = blockIdx.y * 32;
  const int tx = threadIdx.x & 31, ty = threadIdx.x >> 5;   // 32 x 8
  const float* src = Wexp + ((size_t)e * HID + h0) * HID + d0;
  #pragma unroll
  for (int i = 0; i < 4; i++)
    tile[ty + 8 * i][tx] = src[(size_t)(ty + 8 * i) * HID + tx];
  __syncthreads();
  __hip_bfloat16* dst = Wt + ((size_t)e * HID + d0) * HID + h0;
  #pragma unroll
  for (int i = 0; i < 4; i++)
    dst[(size_t)(ty + 8 * i) * HID + tx] = __float2bfloat16(tile[tx][ty + 8 * i]);
}

// ---------------------------------------------------------------- helpers: bf16 split
__device__ inline ushort_t bf16_rne(float f) {
  union { float f; unsigned u; } v; v.f = f;
  unsigned r = v.u + 0x7fffu + ((v.u >> 16) & 1u);
  return (ushort_t)(r >> 16);
}
__device__ inline float bf16_to_f(ushort_t h) {
  union { unsigned u; float f; } v; v.u = ((unsigned)h) << 16;
  return v.f;
}

// ---------------------------------------------------------------- K0a: pack x -> swizzled bf16 hi/lo tiles [mt][kt] 128x64
__global__ __launch_bounds__(256) void k_packA(const float* __restrict__ x,
                                               ushort_t* __restrict__ Ahi,
                                               ushort_t* __restrict__ Alo)
{
  const int kt = blockIdx.x, mt = blockIdx.y;
  const size_t tbase = ((size_t)mt * KT13 + kt) * 8192;
  const int kb = kt * 64;
  #pragma unroll
  for (int i = 0; i < 4; i++) {
    int id = i * 256 + threadIdx.x;             // 1024 chunks of 8
    int r = id >> 3, c = id & 7;
    int row = mt * 128 + r;
    int k0 = kb + c * 8;
    float v[8];
    if (k0 + 8 <= IND) {
      const float4* p = reinterpret_cast<const float4*>(x + (size_t)row * IND + k0);
      float4 a = p[0], b = p[1];
      v[0] = a.x; v[1] = a.y; v[2] = a.z; v[3] = a.w;
      v[4] = b.x; v[5] = b.y; v[6] = b.z; v[7] = b.w;
    } else {
      #pragma unroll
      for (int j = 0; j < 8; j++) v[j] = (k0 + j < IND) ? x[(size_t)row * IND + k0 + j] : 0.f;
    }
    ushort_t hi[8], lo[8];
    #pragma unroll
    for (int j = 0; j < 8; j++) {
      hi[j] = bf16_rne(v[j]);
      lo[j] = bf16_rne(v[j] - bf16_to_f(hi[j]));
    }
    size_t dst = tbase + (size_t)r * 64 + ((c ^ (r & 7)) * 8);
    *reinterpret_cast<uint4*>(Ahi + dst) = *reinterpret_cast<uint4*>(hi);
    *reinterpret_cast<uint4*>(Alo + dst) = *reinterpret_cast<uint4*>(lo);
  }
}

// ---------------------------------------------------------------- K0b: pack W_in^T -> swizzled bf16 hi/lo tiles [nt][kt] 128x64
__global__ __launch_bounds__(256) void k_packB(const float* __restrict__ W,
                                               ushort_t* __restrict__ Bhi,
                                               ushort_t* __restrict__ Blo)
{
  const int kt = blockIdx.x, nt = blockIdx.y;
  const size_t tbase = ((size_t)nt * KT13 + kt) * 8192;
  const int kb = kt * 64;
  #pragma unroll
  for (int i = 0; i < 4; i++) {
    int id = i * 256 + threadIdx.x;
    int r = id >> 3, c = id & 7;                 // r = output col index within tile
    int n = nt * 128 + r;
    int k0 = kb + c * 8;
    float v[8];
    #pragma unroll
    for (int j = 0; j < 8; j++)
      v[j] = (k0 + j < IND) ? W[(size_t)(k0 + j) * HID + n] : 0.f;
    ushort_t hi[8], lo[8];
    #pragma unroll
    for (int j = 0; j < 8; j++) {
      hi[j] = bf16_rne(v[j]);
      lo[j] = bf16_rne(v[j] - bf16_to_f(hi[j]));
    }
    size_t dst = tbase + (size_t)r * 64 + ((c ^ (r & 7)) * 8);
    *reinterpret_cast<uint4*>(Bhi + dst) = *reinterpret_cast<uint4*>(hi);
    *reinterpret_cast<uint4*>(Blo + dst) = *reinterpret_cast<uint4*>(lo);
  }
}

// ---------------------------------------------------------------- K1: proj = x @ W_in + b_in  (split-bf16 3-pass MFMA)
// R1-verified GLD16 staging; XCD-swizzled 1D grid; pm row-sum epilogue
__global__ __launch_bounds__(256, 2) void k_proj2(const ushort_t* __restrict__ Ahi,
                                                  const ushort_t* __restrict__ Alo,
                                                  const ushort_t* __restrict__ Bhi,
                                                  const ushort_t* __restrict__ Blo,
                                                  const float* __restrict__ bias,
                                                  float* __restrict__ out,
                                                  float* __restrict__ pm)
{
  __shared__ __align__(16) ushort_t lds[4 * 8192];   // Ahi | Alo | Bhi | Blo, each 128x64 swizzled
  // bijective XCD swizzle: 768 = 8 XCDs x 96; each XCD gets 16 mt x 6 nt
  const int bid = blockIdx.x;
  const int sid = (bid & 7) * 96 + (bid >> 3);
  const int mt = sid / 6, nt = sid - 6 * mt;
  const int tid = threadIdx.x, lane = tid & 63, w = tid >> 6;
  const int m0 = (w >> 1) * 64, n0 = (w & 1) * 64;
  const int l15 = lane & 15, g = lane >> 4;

  f32x4 acc[4][4];
  #pragma unroll
  for (int i = 0; i < 4; i++)
    #pragma unroll
    for (int j = 0; j < 4; j++) acc[i][j] = (f32x4){0.f, 0.f, 0.f, 0.f};

  const size_t abase = (size_t)mt * KT13 * 8192;
  const size_t bbase = (size_t)nt * KT13 * 8192;

  for (int kt = 0; kt < KT13; kt++) {
    __syncthreads();
    const ushort_t* srcs[4] = { Ahi + abase + (size_t)kt * 8192,
                                Alo + abase + (size_t)kt * 8192,
                                Bhi + bbase + (size_t)kt * 8192,
                                Blo + bbase + (size_t)kt * 8192 };
    #pragma unroll
    for (int buf = 0; buf < 4; buf++) {
      #pragma unroll
      for (int i = 0; i < 4; i++) {
        int off = w * 2048 + i * 512 + lane * 8;   // elements; lane*16B matches HW lane scatter
        GLD16(srcs[buf] + off, &lds[buf * 8192 + w * 2048 + i * 512]);
      }
    }
    asm volatile("s_waitcnt vmcnt(0)");
    __syncthreads();
    #pragma unroll
    for (int ks = 0; ks < 2; ks++) {
      bf16x8 ah[4], al[4], bh[4], bl[4];
      #pragma unroll
      for (int i = 0; i < 4; i++) {
        int ca = ((4 * ks + g) ^ (l15 & 7)) * 8;
        int ra = m0 + 16 * i + l15;
        ah[i] = *reinterpret_cast<const bf16x8*>(&lds[0 * 8192 + ra * 64 + ca]);
        al[i] = *reinterpret_cast<const bf16x8*>(&lds[1 * 8192 + ra * 64 + ca]);
        int rb = n0 + 16 * i + l15;
        bh[i] = *reinterpret_cast<const bf16x8*>(&lds[2 * 8192 + rb * 64 + ca]);
        bl[i] = *reinterpret_cast<const bf16x8*>(&lds[3 * 8192 + rb * 64 + ca]);
      }
      #pragma unroll
      for (int i = 0; i < 4; i++)
        #pragma unroll
        for (int j = 0; j < 4; j++) {
          acc[i][j] = __builtin_amdgcn_mfma_f32_16x16x32_bf16(ah[i], bh[j], acc[i][j], 0, 0, 0);
          acc[i][j] = __builtin_amdgcn_mfma_f32_16x16x32_bf16(ah[i], bl[j], acc[i][j], 0, 0, 0);
          acc[i][j] = __builtin_amdgcn_mfma_f32_16x16x32_bf16(al[i], bh[j], acc[i][j], 0, 0, 0);
        }
    }
  }
  // epilogue: C layout col=lane&15, row=(lane>>4)*4+reg
  float bl[4];
  #pragma unroll
  for (int j = 0; j < 4; j++) bl[j] = bias[nt * 128 + n0 + 16 * j + l15];
  #pragma unroll
  for (int i = 0; i < 4; i++) {
    #pragma unroll
    for (int q = 0; q < 4; q++) {
      int m = mt * 128 + m0 + 16 * i + g * 4 + q;
      #pragma unroll
      for (int j = 0; j < 4; j++) {
        int n = nt * 128 + n0 + 16 * j + l15;
        out[(size_t)m * HID + n] = acc[i][j][q] + bl[j];
      }
    }
  }
  // deterministic row-sum partials for mean: 12 slots/row (6 nt x 2 wave-halves)
  const float blsum = bl[0] + bl[1] + bl[2] + bl[3];
  const size_t pslot = (size_t)(nt * 2 + (w & 1)) * BATCH;
  #pragma unroll
  for (int i = 0; i < 4; i++) {
    #pragma unroll
    for (int q = 0; q < 4; q++) {
      float s = acc[i][0][q] + acc[i][1][q] + acc[i][2][q] + acc[i][3][q] + blsum;
      s += __shfl_xor(s, 1); s += __shfl_xor(s, 2);
      s += __shfl_xor(s, 4); s += __shfl_xor(s, 8);
      if (l15 == 0)
        pm[pslot + mt * 128 + m0 + 16 * i + g * 4 + q] = s;
    }
  }
}

// ---------------------------------------------------------------- K1c: enh = proj + feats @ W_ph + b_ph  (in place; means fused)
__global__ __launch_bounds__(256) void k_phasor(const float* __restrict__ pm,
                                                const float* __restrict__ Wph,
                                                const float* __restrict__ bph,
                                                float* __restrict__ enh)
{
  __shared__ float Fs[64][132];   // [k][m] transposed feats
  __shared__ float Ws[64][128];   // [k][n]
  __shared__ float mlds[128];
  const int t  = threadIdx.x;
  const int bm = blockIdx.y * 128, bn = blockIdx.x * 128;
  if (t < 128) {
    float s = 0.f;
    #pragma unroll
    for (int k = 0; k < 12; k++) s += pm[(size_t)k * BATCH + bm + t];
    mlds[t] = s * (1.0f / 768.0f);
  }
  __syncthreads();
  {
    const int r = t >> 1;
    const float mn = mlds[r];
    if ((t & 1) == 0) {
      #pragma unroll
      for (int j = 0; j < 32; j++) Fs[j][r] = sinf(mn * (7.0f * (j + 1)));
    } else {
      #pragma unroll
      for (int j = 0; j < 32; j++) Fs[32 + j][r] = cosf(mn * (7.0f * (j + 1)));
    }
  }
  #pragma unroll
  for (int i = 0; i < 8; i++) {
    int f4 = i * 256 + t;
    int k = f4 >> 5, n4 = (f4 & 31) * 4;
    *reinterpret_cast<float4*>(&Ws[k][n4]) =
        *reinterpret_cast<const float4*>(Wph + (size_t)k * HID + bn + n4);
  }
  __syncthreads();

  const int m0 = (t >> 4) * 8, n0 = (t & 15) * 8;
  float acc[8][8];
  #pragma unroll
  for (int i = 0; i < 8; i++)
    #pragma unroll
    for (int j = 0; j < 8; j++) acc[i][j] = 0.f;
  #pragma unroll 4
  for (int k = 0; k < 64; k++) {
    float a[8], b[8];
    *reinterpret_cast<float4*>(&a[0]) = *reinterpret_cast<const float4*>(&Fs[k][m0]);
    *reinterpret_cast<float4*>(&a[4]) = *reinterpret_cast<const float4*>(&Fs[k][m0 + 4]);
    *reinterpret_cast<float4*>(&b[0]) = *reinterpret_cast<const float4*>(&Ws[k][n0]);
    *reinterpret_cast<float4*>(&b[4]) = *reinterpret_cast<const float4*>(&Ws[k][n0 + 4]);
    #pragma unroll
    for (int i = 0; i < 8; i++)
      #pragma unroll
      for (int j = 0; j < 8; j++) acc[i][j] = fmaf(a[i], b[j], acc[i][j]);
  }
  float bl[8];
  #pragma unroll
  for (int j = 0; j < 8; j++) bl[j] = bph[bn + n0 + j];
  #pragma unroll
  for (int i = 0; i < 8; i++) {
    float* rowp = enh + (size_t)(bm + m0 + i) * HID + bn + n0;
    float4 p0 = *reinterpret_cast<float4*>(rowp);
    float4 p1 = *reinterpret_cast<float4*>(rowp + 4);
    p0.x += acc[i][0] + bl[0]; p0.y += acc[i][1] + bl[1];
    p0.z += acc[i][2] + bl[2]; p0.w += acc[i][3] + bl[3];
    p1.x += acc[i][4] + bl[4]; p1.y += acc[i][5] + bl[5];
    p1.z += acc[i][6] + bl[6]; p1.w += acc[i][7] + bl[7];
    *reinterpret_cast<float4*>(rowp)     = p0;
    *reinterpret_cast<float4*>(rowp + 4) = p1;
  }
}

// ---------------------------------------------------------------- K2: top-5 gains, attended(bf16), gate partials, colsum partials
__global__ __launch_bounds__(256) void k_attend(const float* __restrict__ enh,
                                                const float* __restrict__ Wg,
                                                __hip_bfloat16* __restrict__ attb,
                                                float* __restrict__ glog,
                                                float* __restrict__ partials)
{
  __shared__ float WgT[8][768];
  __shared__ float cs[4][768];
  const int t = threadIdx.x, lane = t & 63, w = t >> 6;
  for (int i = t; i < 768 * 8; i += 256) { int c = i >> 3, e = i & 7; WgT[e][c] = Wg[i]; }
  for (int i = t; i < 4 * 768; i += 256) cs[i / 768][i % 768] = 0.f;
  __syncthreads();

  for (int rr = 0; rr < 8; ++rr) {
    const int row = blockIdx.x * 32 + rr * 4 + w;
    const float* er = enh + (size_t)row * HID;
    float o[12], s[12];
    #pragma unroll
    for (int j = 0; j < 12; j++) { o[j] = er[lane + 64 * j]; s[j] = o[j]; }

    int wc[5];
    #pragma unroll
    for (int k = 0; k < 5; k++) {
      float v = -3.4e38f; int c = 0x7fffffff;
      #pragma unroll
      for (int j = 0; j < 12; j++)
        if (s[j] > v) { v = s[j]; c = lane + 64 * j; }          // ascending j: low idx on tie
      #pragma unroll
      for (int off = 32; off; off >>= 1) {
        float ov = __shfl_xor(v, off); int oc = __shfl_xor(c, off);
        if (ov > v || (ov == v && oc < c)) { v = ov; c = oc; }  // jax tie rule: lower index
      }
      wc[k] = c;
      if (lane == (c & 63)) {
        #pragma unroll
        for (int j = 0; j < 12; j++) if (j == (c >> 6)) s[j] = -3.4e38f;
      }
    }

    float a[12];
    #pragma unroll
    for (int j = 0; j < 12; j++) a[j] = o[j];
    float wv = 1.0f;
    #pragma unroll
    for (int k = 0; k < 5; k++) {
      int c = wc[k];
      if (lane == (c & 63)) {
        #pragma unroll
        for (int j = 0; j < 12; j++) if (j == (c >> 6)) a[j] = o[j] * (1.0f + wv);
      }
      wv *= 0.7f;
    }
    #pragma unroll
    for (int j = 0; j < 12; j++)
      attb[(size_t)row * HID + lane + 64 * j] = __float2bfloat16(a[j]);
    #pragma unroll
    for (int j = 0; j < 12; j++) cs[w][lane + 64 * j] += a[j];

    float p[8];
    #pragma unroll
    for (int e = 0; e < 8; e++) p[e] = 0.f;
    #pragma unroll
    for (int j = 0; j < 12; j++) {
      int c = lane + 64 * j;
      #pragma unroll
      for (int e = 0; e < 8; e++) p[e] = fmaf(a[j], WgT[e][c], p[e]);
    }
    #pragma unroll
    for (int e = 0; e < 8; e++) {
      #pragma unroll
      for (int off = 32; off; off >>= 1) p[e] += __shfl_xor(p[e], off);
    }
    if (lane == 0) {
      #pragma unroll
      for (int e = 0; e < 8; e++) glog[(size_t)row * 8 + e] = p[e];
    }
  }
  __syncthreads();
  for (int i = t; i < 768; i += 256)
    partials[(size_t)blockIdx.x * 768 + i] = cs[0][i] + cs[1][i] + cs[2][i] + cs[3][i];
}

// ---------------------------------------------------------------- K3: thal + pbias + b_gate -> add8[8]
__global__ void k_thal(const float* __restrict__ partials,
                       const float* __restrict__ Wth, const float* __restrict__ bth,
                       const float* __restrict__ Wpm, const float* __restrict__ bpm,
                       const float* __restrict__ bgate, float* __restrict__ add8)
{
  __shared__ float cm[768];
  __shared__ float th[8];
  const int t = threadIdx.x;
  float s = 0.f;
  #pragma unroll 8
  for (int b = 0; b < 512; b++) s += partials[(size_t)b * 768 + t];
  cm[t] = s * (1.0f / 16384.0f);
  __syncthreads();
  if (t < 256) {
    int e = t >> 5, l = t & 31;
    float ps = 0.f;
    for (int c = l; c < 768; c += 32) ps = fmaf(cm[c], Wth[(size_t)c * 8 + e], ps);
    #pragma unroll
    for (int off = 16; off; off >>= 1) ps += __shfl_xor(ps, off);
    if (l == 0) th[e] = ps + bth[e];
  }
  __syncthreads();
  if (t < 8) {
    const float TR[5] = {0.6f, 0.6f, 0.5f, 0.5f, 0.4f};
    float pb = bpm[t];
    #pragma unroll
    for (int i = 0; i < 5; i++) pb = fmaf(TR[i], Wpm[i * 8 + t], pb);
    add8[t] = th[t] + pb + bgate[t];
  }
}

// ---------------------------------------------------------------- K4: gate top-2 + softmax + counts
__global__ __launch_bounds__(256) void k_route(const float* __restrict__ glog,
                                               const float* __restrict__ add8,
                                               float* __restrict__ rw,
                                               unsigned char* __restrict__ re,
                                               int* __restrict__ counts)
{
  __shared__ float a8[8];
  __shared__ int lc[8];
  const int t = threadIdx.x;
  if (t < 8) { a8[t] = add8[t]; lc[t] = 0; }
  __syncthreads();
  const int row = blockIdx.x * 256 + t;
  const float4* gp = reinterpret_cast<const float4*>(glog + (size_t)row * 8);
  float4 g0 = gp[0], g1 = gp[1];
  float l[8] = { g0.x + a8[0], g0.y + a8[1], g0.z + a8[2], g0.w + a8[3],
                 g1.x + a8[4], g1.y + a8[5], g1.z + a8[6], g1.w + a8[7] };
  float v0 = l[0], v1 = -3.4e38f; int i0 = 0, i1 = 0;
  #pragma unroll
  for (int e = 1; e < 8; e++) {
    if (l[e] > v0)      { v1 = v0; i1 = i0; v0 = l[e]; i0 = e; }
    else if (l[e] > v1) { v1 = l[e]; i1 = e; }
  }
  float ex = expf(v1 - v0);
  float inv = 1.0f / (1.0f + ex);
  rw[row * 2] = inv; rw[row * 2 + 1] = ex * inv;
  re[row * 2] = (unsigned char)i0; re[row * 2 + 1] = (unsigned char)i1;
  atomicAdd(&lc[i0], 1); atomicAdd(&lc[i1], 1);
  __syncthreads();
  if (t < 8) atomicAdd(&counts[t], lc[t]);
}

// ---------------------------------------------------------------- K4b: prefix sums -> meta
// meta layout: [0..8]=offs, [9..17]=tile_start, [18]=total_tiles, [19..26]=cursors
__global__ void k_prefix(const int* __restrict__ counts, int* __restrict__ meta)
{
  if (threadIdx.x == 0) {
    int o = 0, tt = 0;
    for (int e = 0; e < 8; e++) {
      meta[e] = o; meta[9 + e] = tt; meta[19 + e] = o;
      o += counts[e]; tt += (counts[e] + 127) >> 7;
    }
    meta[8] = o; meta[17] = tt; meta[18] = tt;
  }
}

// ---------------------------------------------------------------- K4c: bucket-scatter rows into per-expert segments (+ inverse)
__global__ __launch_bounds__(256) void k_scatter(const unsigned char* __restrict__ re,
                                                 int* __restrict__ meta,
                                                 int* __restrict__ perm,
                                                 int* __restrict__ inv)
{
  __shared__ int lc[8], base[8];
  const int t = threadIdx.x;
  if (t < 8) lc[t] = 0;
  __syncthreads();
  const int row = blockIdx.x * 256 + t;
  const int e0 = re[row * 2], e1 = re[row * 2 + 1];
  const int p0 = atomicAdd(&lc[e0], 1);
  const int p1 = atomicAdd(&lc[e1], 1);
  __syncthreads();
  if (t < 8) base[t] = atomicAdd(&meta[19 + t], lc[t]);
  __syncthreads();
  const int s0 = base[e0] + p0;
  const int s1 = base[e1] + p1;
  perm[s0] = row * 2;     inv[row * 2]     = s0;
  perm[s1] = row * 2 + 1; inv[row * 2 + 1] = s1;
}

// ---------------------------------------------------------------- K5: routed expert GEMM, bf16 MFMA, 128x128 tiles
// 512-thread blocks (8 waves, 2x4 wave grid, 64x32/wave) for 2x TLP; hoisted gather
// addressing (rid read once, base pointers advanced by kb); double-buffered GLD16
// with counted vmcnt; XCD-grouping swizzle (6 nb-blocks of a tile on one XCD)
__global__ __launch_bounds__(512) void k_expert(const unsigned short* __restrict__ attb,
                                                const unsigned short* __restrict__ Wt,
                                                const float* __restrict__ bexp,
                                                const float* __restrict__ rw,
                                                const int* __restrict__ perm,
                                                const int* __restrict__ meta,
                                                ushort_t* __restrict__ ctxP)
{
  // 1584 blocks = 8 XCDs x (33 tiles x 6 nb), nb innermost per XCD
  const int l = blockIdx.x;
  const int xcd = l & 7, idx = l >> 3;
  const int tb = xcd + 8 * (idx / 6);
  const int nb = (idx - 6 * (idx / 6)) * 128;
  if (tb >= meta[18]) return;
  __shared__ __align__(16) ushort_t sst[2][2][8192];   // [buf][A/B][128x64]; sst[0] reused as C tile
  __shared__ int rid[128];
  __shared__ float gws[128];
  __shared__ float bxs[128];

  const int* tst = meta + 9;
  int e = 0;
  #pragma unroll
  for (int i = 1; i < 8; i++) if (tb >= tst[i]) e = i;
  const int tix  = tb - tst[e];
  const int off  = meta[e];
  const int cnt  = meta[e + 1] - off;
  const int rbase = off + tix * 128;
  const int vcnt  = min(128, cnt - tix * 128);
  const int tid = threadIdx.x;

  if (tid < 128) {
    if (tid < vcnt) {
      int p = perm[rbase + tid];
      rid[tid] = p >> 1; gws[tid] = rw[p];
    } else {
      rid[tid] = 0; gws[tid] = 0.f;
    }
    bxs[tid] = bexp[(size_t)e * HID + nb + tid];
  }
  __syncthreads();

  const int lane = tid & 63, w = tid >> 6;             // 8 waves
  const int m0 = (w >> 2) * 64, n0 = (w & 3) * 32;     // 2x4 wave grid over 128x128
  const int l15 = lane & 15, g = lane >> 4;
  const unsigned short* wbase = Wt + ((size_t)e * HID + nb) * HID;

  // hoisted gather addressing: chunk row = tid>>3 (+64), col swizzle const per thread
  const int chr = tid >> 3;                            // 0..63
  const int sc  = ((tid & 7) ^ (chr & 7)) * 8;         // pre-swizzled source col (elems)
  const int ra0 = rid[chr], ra1 = rid[chr + 64];       // read ONCE (after barrier)
  const ushort_t* asrc0 = attb  + (size_t)ra0 * HID + sc;
  const ushort_t* asrc1 = attb  + (size_t)ra1 * HID + sc;
  const ushort_t* bsrc0 = wbase + (size_t)chr * HID + sc;
  const ushort_t* bsrc1 = wbase + (size_t)(chr + 64) * HID + sc;
  const int dst0 = (0 * 512 + w * 64) * 8;             // wave-uniform LDS bases
  const int dst1 = (1 * 512 + w * 64) * 8;

#define ESTAGE(kb, b)                                                          \
  { GLD16(asrc0 + (kb), &sst[b][0][dst0]);                                     \
    GLD16(asrc1 + (kb), &sst[b][0][dst1]);                                     \
    GLD16(bsrc0 + (kb), &sst[b][1][dst0]);                                     \
    GLD16(bsrc1 + (kb), &sst[b][1][dst1]); }

  f32x4 acc[4][2];
  #pragma unroll
  for (int i = 0; i < 4; i++)
    #pragma unroll
    for (int j = 0; j < 2; j++) acc[i][j] = (f32x4){0.f, 0.f, 0.f, 0.f};

  ESTAGE(0, 0);
  for (int t = 0; t < 12; t++) {
    const int cb = t & 1;
    if (t < 11) {
      ESTAGE((t + 1) * 64, cb ^ 1);
      asm volatile("s_waitcnt vmcnt(4)" ::: "memory");   // tile-t staged; t+1 stays in flight
    } else {
      asm volatile("s_waitcnt vmcnt(0)" ::: "memory");
    }
    __builtin_amdgcn_s_barrier();
    const ushort_t* As = &sst[cb][0][0];
    const ushort_t* Bs = &sst[cb][1][0];
    #pragma unroll
    for (int ks = 0; ks < 2; ks++) {
      bf16x8 af[4], bfr[2];
      #pragma unroll
      for (int i = 0; i < 4; i++) {
        int ca = (((4 * ks + g) ^ (l15 & 7)) * 8);
        af[i] = *reinterpret_cast<const bf16x8*>(As + (m0 + 16 * i + l15) * 64 + ca);
      }
      #pragma unroll
      for (int j = 0; j < 2; j++) {
        int ca = (((4 * ks + g) ^ (l15 & 7)) * 8);
        bfr[j] = *reinterpret_cast<const bf16x8*>(Bs + (n0 + 16 * j + l15) * 64 + ca);
      }
      #pragma unroll
      for (int i = 0; i < 4; i++)
        #pragma unroll
        for (int j = 0; j < 2; j++)
          acc[i][j] = __builtin_amdgcn_mfma_f32_16x16x32_bf16(af[i], bfr[j], acc[i][j], 0, 0, 0);
    }
    __builtin_amdgcn_s_barrier();
  }
#undef ESTAGE

  // epilogue: stage C tile (gw * (acc + bias) -> bf16) in LDS, then contiguous slot-row stores.
  unsigned short* Cs = &sst[0][0][0];    // [128][128] bf16 = 32 KB
  __syncthreads();
  #pragma unroll
  for (int i = 0; i < 4; i++) {
    #pragma unroll
    for (int q = 0; q < 4; q++) {
      int m = m0 + 16 * i + g * 4 + q;
      float gwv = gws[m];
      #pragma unroll
      for (int j = 0; j < 2; j++) {
        int n = n0 + 16 * j + l15;
        Cs[m * 128 + n] = bf16_rne(gwv * (acc[i][j][q] + bxs[n]));
      }
    }
  }
  __syncthreads();
  #pragma unroll
  for (int c = 0; c < 4; c++) {
    int r = w * 16 + c * 4 + (lane >> 4);     // 8 waves x 16 rows; 4 rows/instr, 256B/row
    if (r < vcnt) {
      uint4 v = *reinterpret_cast<const uint4*>(Cs + r * 128 + l15 * 8);
      *reinterpret_cast<uint4*>(ctxP + (size_t)(rbase + r) * HID + nb + l15 * 8) = v;
    }
  }
}

// ---------------------------------------------------------------- K6: out = (ctxP[inv0] + ctxP[inv1]) @ W_out + b_out
__global__ __launch_bounds__(256) void k_out(const ushort_t* __restrict__ ctxP,
                                             const int* __restrict__ inv,
                                             const float* __restrict__ Wout,
                                             const float* __restrict__ bout,
                                             float* __restrict__ out)
{
  __shared__ float wT[10][768];
  const int t = threadIdx.x, lane = t & 63, w = t >> 6;
  for (int i = t; i < 7680; i += 256) { int cl = i / 768, d = i - cl * 768; wT[cl][d] = Wout[(size_t)d * 10 + cl]; }
  __syncthreads();
  for (int rr = 0; rr < 8; ++rr) {
    const int row = blockIdx.x * 32 + rr * 4 + w;
    const int s0 = inv[row * 2], s1 = inv[row * 2 + 1];
    const ushort_t* p0 = ctxP + (size_t)s0 * HID;
    const ushort_t* p1 = ctxP + (size_t)s1 * HID;
    float cd[12];
    #pragma unroll
    for (int j = 0; j < 12; j++)
      cd[j] = bf16_to_f(p0[lane + 64 * j]) + bf16_to_f(p1[lane + 64 * j]);
    float p[10];
    #pragma unroll
    for (int cl = 0; cl < 10; cl++) {
      float ps = 0.f;
      #pragma unroll
      for (int j = 0; j < 12; j++) ps = fmaf(cd[j], wT[cl][lane + 64 * j], ps);
      #pragma unroll
      for (int off = 32; off; off >>= 1) ps += __shfl_xor(ps, off);
      p[cl] = ps;
    }
    if (lane == 0) {
      #pragma unroll
      for (int cl = 0; cl < 10; cl++) out[(size_t)row * 10 + cl] = p[cl] + bout[cl];
    }
  }
}

// ---------------------------------------------------------------- launch
extern "C" void kernel_launch(void* const* d_in, const int* in_sizes, int n_in,
                              void* d_out, int out_size, void* d_ws, size_t ws_size,
                              hipStream_t stream)
{
  const float* x     = (const float*)d_in[0];
  const float* W_in  = (const float*)d_in[1];
  const float* b_in  = (const float*)d_in[2];
  const float* W_ph  = (const float*)d_in[3];
  const float* b_ph  = (const float*)d_in[4];
  const float* W_g   = (const float*)d_in[5];
  const float* b_g   = (const float*)d_in[6];
  const float* W_exp = (const float*)d_in[7];
  const float* b_exp = (const float*)d_in[8];
  const float* W_th  = (const float*)d_in[9];
  const float* b_th  = (const float*)d_in[10];
  const float* W_pm  = (const float*)d_in[11];
  const float* b_pm  = (const float*)d_in[12];
  const float* W_out = (const float*)d_in[13];
  const float* b_out = (const float*)d_in[14];
  float* out = (float*)d_out;

  char* ws = (char*)d_ws;
  size_t off = 0;
  float* enh = (float*)(ws + off); off += (size_t)BATCH * HID * 4;     // proj/enh; later ctxP (bf16, 32768 rows)
  char*  r1  = ws + off;           off += (size_t)2 * BATCH * KT13 * 64 * 2;  // 54.5 MB multi-use region
  // r1 phase 1 (packA..proj2): Ahi | Alo
  ushort_t* Ahi = (ushort_t*)r1;
  ushort_t* Alo = Ahi + (size_t)BATCH * KT13 * 64;
  // r1 phase 2 (wtrans..expert): attb | Wt   (Ahi/Alo dead after k_proj2)
  __hip_bfloat16* attb = (__hip_bfloat16*)r1;
  __hip_bfloat16* Wt   = (__hip_bfloat16*)(r1 + (size_t)BATCH * HID * 2);
  float* glog     = (float*)(ws + off); off += (size_t)BATCH * 8 * 4;
  float* partials = (float*)(ws + off); off += (size_t)512 * 768 * 4;
  float* pm       = (float*)(ws + off); off += (size_t)12 * BATCH * 4;
  float* add8     = (float*)(ws + off); off += 256;
  float* rw       = (float*)(ws + off); off += (size_t)BATCH * 2 * 4;
  unsigned char* re = (unsigned char*)(ws + off); off += (size_t)BATCH * 2;
  int* counts = (int*)(ws + off); off += 256;
  int* meta   = (int*)(ws + off); off += 256;
  int* perm   = (int*)(ws + off); off += (size_t)BATCH * 2 * 4;
  int* invp   = (int*)(ws + off); off += (size_t)BATCH * 2 * 4;
  ushort_t* Bhi = (ushort_t*)(ws + off); off += (size_t)KT13 * 64 * HID * 2;
  ushort_t* Blo = (ushort_t*)(ws + off); off += (size_t)KT13 * 64 * HID * 2;
  // permuted bf16 context (32768 slots x 768) reuses the enh region (enh dead after k_attend)
  ushort_t* ctxP = (ushort_t*)enh;                                      // 50.3 MB, fits exactly

  hipMemsetAsync(counts, 0, 32, stream);
  k_packB <<<dim3(13, 6),     256, 0, stream>>>(W_in, Bhi, Blo);
  k_packA <<<dim3(13, 128),   256, 0, stream>>>(x, Ahi, Alo);
  k_proj2 <<<768,             256, 0, stream>>>(Ahi, Alo, Bhi, Blo, b_in, enh, pm);
  k_wtrans<<<dim3(24, 24, 8), 256, 0, stream>>>(W_exp, Wt);            // after proj2: Wt aliases r1 tail
  k_phasor<<<dim3(6, 128),    256, 0, stream>>>(pm, W_ph, b_ph, enh);
  k_attend<<<512,             256, 0, stream>>>(enh, W_g, attb, glog, partials);
  k_thal  <<<1,               768, 0, stream>>>(partials, W_th, b_th, W_pm, b_pm, b_g, add8);
  k_route <<<64,              256, 0, stream>>>(glog, add8, rw, re, counts);
  k_prefix<<<1,                64, 0, stream>>>(counts, meta);
  k_scatter<<<64,             256, 0, stream>>>(re, meta, perm, invp);
  k_expert<<<1584,            512, 0, stream>>>((const unsigned short*)attb, (const unsigned short*)Wt,
                                                b_exp, rw, perm, meta, ctxP);
  k_out   <<<512,             256, 0, stream>>>(ctxP, invp, W_out, b_out, out);
}